// Round 1
// baseline (880.580 us; speedup 1.0000x reference)
//
#include <hip/hip_runtime.h>

typedef unsigned short u16;
typedef __attribute__((ext_vector_type(8))) short short8;
typedef __attribute__((ext_vector_type(4))) float f32x4;

// ---------- helpers ----------
__device__ __forceinline__ u16 f2bf(float f) {
  union { float f; unsigned int u; } v; v.f = f;
  unsigned int r = v.u + 0x7FFFu + ((v.u >> 16) & 1u);  // RNE
  return (u16)(r >> 16);
}

__device__ __forceinline__ void gload_lds16(const void* g, void* l) {
  __builtin_amdgcn_global_load_lds((const __attribute__((address_space(1))) void*)g,
                                   (__attribute__((address_space(3))) void*)l, 16, 0, 0);
}

// ---------- f32 -> bf16 convert ----------
__global__ __launch_bounds__(256) void cvt_f32_bf16(const float* __restrict__ in,
                                                    u16* __restrict__ out, long n) {
  long i = ((long)blockIdx.x * 256 + threadIdx.x) * 4;
  if (i + 3 < n) {
    float4 v = *(const float4*)(in + i);
    unsigned long long p = (unsigned long long)f2bf(v.x) |
                           ((unsigned long long)f2bf(v.y) << 16) |
                           ((unsigned long long)f2bf(v.z) << 32) |
                           ((unsigned long long)f2bf(v.w) << 48);
    *(unsigned long long*)(out + i) = p;
  }
}

// ---------- weight transpose+convert: W[K,N] f32 -> WT[N,K] bf16 ----------
__global__ __launch_bounds__(256) void wtrans(const float* __restrict__ W,
                                              u16* __restrict__ WT, int K, int N) {
  __shared__ float t[32][33];
  int n0 = blockIdx.x * 32, k0 = blockIdx.y * 32;
  int tx = threadIdx.x, ty = threadIdx.y;
#pragma unroll
  for (int r = 0; r < 4; r++)
    t[ty + r * 8][tx] = W[(long)(k0 + ty + r * 8) * N + n0 + tx];
  __syncthreads();
#pragma unroll
  for (int r = 0; r < 4; r++)
    WT[(long)(n0 + ty + r * 8) * K + k0 + tx] = f2bf(t[tx][ty + r * 8]);
}

// ---------- V transpose: [b, n, head_off + h*64 + d] -> [bh][d][n] ----------
__global__ __launch_bounds__(256) void vtrans(const u16* __restrict__ src,
                                              u16* __restrict__ dst,
                                              int rows, int rstride, int head_off, int H) {
  __shared__ u16 t[64][65];
  int bh = blockIdx.y;
  int b = bh / H, h = bh % H;
  long n0 = (long)blockIdx.x * 64;
  const u16* s = src + (long)b * rows * rstride + head_off + h * 64;
  int q = threadIdx.x >> 6, ln = threadIdx.x & 63;
#pragma unroll
  for (int r = 0; r < 16; r++) {
    int nl = q * 16 + r;
    t[nl][ln] = s[(n0 + nl) * (long)rstride + ln];
  }
  __syncthreads();
  u16* d = dst + (long)bh * 64 * rows;
#pragma unroll
  for (int r = 0; r < 16; r++) {
    int dd = q * 16 + r;
    d[(long)dd * rows + n0 + ln] = t[ln][dd];
  }
}

// ---------- bf16 GEMM: C[M,N] = A[M,K] * BT[N,K]^T + bias ----------
// 128x128 tile, BK=32, 4 waves (2x2 of 64x64), mfma_f32_16x16x32_bf16
__global__ __launch_bounds__(256) void gemm_bt(const u16* __restrict__ A,
                                               const u16* __restrict__ BT,
                                               const float* __restrict__ bias,
                                               float* __restrict__ outF,
                                               u16* __restrict__ outB,
                                               int M, int N, int K, int gelu) {
  __shared__ u16 As[128 * 32];
  __shared__ u16 Bs[128 * 32];
  const int tid = threadIdx.x;
  const int l = tid & 63;
  const int w = tid >> 6;
  const int wr = w >> 1, wc = w & 1;
  const long m0 = (long)blockIdx.x * 128, n0 = (long)blockIdx.y * 128;
  const int lr = l & 15, lg = l >> 4;

  const u16* Ag = A + (m0 + (tid >> 2)) * (long)K + (tid & 3) * 8;
  const u16* Bg = BT + (n0 + (tid >> 2)) * (long)K + (tid & 3) * 8;

  f32x4 acc[4][4];
#pragma unroll
  for (int i = 0; i < 4; i++)
#pragma unroll
    for (int j = 0; j < 4; j++) acc[i][j] = (f32x4){0.f, 0.f, 0.f, 0.f};

  for (int k0 = 0; k0 < K; k0 += 32) {
    gload_lds16(Ag + k0, As + tid * 8);
    gload_lds16(Ag + k0 + 64 * (long)K, As + 2048 + tid * 8);
    gload_lds16(Bg + k0, Bs + tid * 8);
    gload_lds16(Bg + k0 + 64 * (long)K, Bs + 2048 + tid * 8);
    __syncthreads();
    short8 a[4], b[4];
#pragma unroll
    for (int mm = 0; mm < 4; mm++)
      a[mm] = *(const short8*)&As[(wr * 64 + mm * 16 + lr) * 32 + lg * 8];
#pragma unroll
    for (int nn = 0; nn < 4; nn++)
      b[nn] = *(const short8*)&Bs[(wc * 64 + nn * 16 + lr) * 32 + lg * 8];
#pragma unroll
    for (int mm = 0; mm < 4; mm++)
#pragma unroll
      for (int nn = 0; nn < 4; nn++)
        acc[mm][nn] = __builtin_amdgcn_mfma_f32_16x16x32_bf16(a[mm], b[nn], acc[mm][nn], 0, 0, 0);
    __syncthreads();
  }

#pragma unroll
  for (int nn = 0; nn < 4; nn++) {
    const long col = n0 + wc * 64 + nn * 16 + lr;
    const float bv = bias ? bias[col] : 0.f;
#pragma unroll
    for (int mm = 0; mm < 4; mm++) {
#pragma unroll
      for (int i = 0; i < 4; i++) {
        const long row = m0 + wr * 64 + mm * 16 + lg * 4 + i;
        float v = acc[mm][nn][i] + bv;
        if (gelu) v = 0.5f * v * (1.f + erff(v * 0.70710678118654752f));
        if (outF) outF[row * N + col] = v;
        if (outB) outB[row * N + col] = f2bf(v);
      }
    }
  }
}

// ---------- flash attention ----------
// grid: (Nq/64, B*H). 4 waves/block, each wave owns 16 q rows.
// q: [b, n, h*64 + d] via strides; k same; vt: [bh][64][Nk]; y: [b, n, h*64+dv]
template <bool CAUSAL>
__global__ __launch_bounds__(256) void attn(const u16* __restrict__ qb, long q_bstride, int q_rstride,
                                            const u16* __restrict__ kbp, long k_bstride, int k_rstride,
                                            const u16* __restrict__ vt,
                                            u16* __restrict__ yb, long y_bstride, int y_rstride,
                                            int Nk, int H) {
  __shared__ u16 plds[4][16 * 32];
  const int tid = threadIdx.x, w = tid >> 6, l = tid & 63;
  const int bh = blockIdx.y, b = bh / H, h = bh % H;
  const int qr = blockIdx.x * 64 + w * 16;
  const u16* qp = qb + (long)b * q_bstride + h * 64;
  const u16* kp = kbp + (long)b * k_bstride + h * 64;
  const u16* vp = vt + (long)bh * 64 * Nk;
  const int lr = l & 15, lg = l >> 4;

  short8 qf[2];
#pragma unroll
  for (int kk = 0; kk < 2; kk++)
    qf[kk] = *(const short8*)(qp + (long)(qr + lr) * q_rstride + kk * 32 + lg * 8);

  f32x4 o[4];
#pragma unroll
  for (int nt = 0; nt < 4; nt++) o[nt] = (f32x4){0.f, 0.f, 0.f, 0.f};
  float mrow[4] = {-INFINITY, -INFINITY, -INFINITY, -INFINITY};
  float lrow[4] = {0.f, 0.f, 0.f, 0.f};

  const int nkb = CAUSAL ? ((qr + 47) >> 5) : (Nk >> 5);

  for (int t0 = 0; t0 < nkb; t0++) {
    const int kb0 = t0 * 32;
    f32x4 s[2];
#pragma unroll
    for (int ct = 0; ct < 2; ct++) {
      short8 kf0 = *(const short8*)(kp + (long)(kb0 + ct * 16 + lr) * k_rstride + lg * 8);
      short8 kf1 = *(const short8*)(kp + (long)(kb0 + ct * 16 + lr) * k_rstride + 32 + lg * 8);
      f32x4 z = (f32x4){0.f, 0.f, 0.f, 0.f};
      z = __builtin_amdgcn_mfma_f32_16x16x32_bf16(qf[0], kf0, z, 0, 0, 0);
      z = __builtin_amdgcn_mfma_f32_16x16x32_bf16(qf[1], kf1, z, 0, 0, 0);
      s[ct] = z;
    }
    float p0s[4], p1s[4];
#pragma unroll
    for (int i = 0; i < 4; i++) {
      float s0 = s[0][i] * 0.125f, s1 = s[1][i] * 0.125f;
      if (CAUSAL) {
        int row = qr + lg * 4 + i;
        if (kb0 + lr > row) s0 = -INFINITY;
        if (kb0 + 16 + lr > row) s1 = -INFINITY;
      }
      float mx = fmaxf(s0, s1);
#pragma unroll
      for (int off = 1; off < 16; off <<= 1) mx = fmaxf(mx, __shfl_xor(mx, off, 64));
      float mnew = fmaxf(mrow[i], mx);
      float alpha = expf(mrow[i] - mnew);
      mrow[i] = mnew;
      float p0 = expf(s0 - mnew), p1 = expf(s1 - mnew);
      float ps = p0 + p1;
#pragma unroll
      for (int off = 1; off < 16; off <<= 1) ps += __shfl_xor(ps, off, 64);
      lrow[i] = lrow[i] * alpha + ps;
#pragma unroll
      for (int nt = 0; nt < 4; nt++) o[nt][i] *= alpha;
      p0s[i] = p0; p1s[i] = p1;
    }
    u16* pl = plds[w];
#pragma unroll
    for (int i = 0; i < 4; i++) {
      pl[(lg * 4 + i) * 32 + lr] = f2bf(p0s[i]);
      pl[(lg * 4 + i) * 32 + 16 + lr] = f2bf(p1s[i]);
    }
    short8 pa = *(const short8*)&pl[lr * 32 + lg * 8];
#pragma unroll
    for (int nt = 0; nt < 4; nt++) {
      short8 vf = *(const short8*)(vp + (long)(nt * 16 + lr) * Nk + kb0 + lg * 8);
      o[nt] = __builtin_amdgcn_mfma_f32_16x16x32_bf16(pa, vf, o[nt], 0, 0, 0);
    }
  }

  u16* yp = yb + (long)b * y_bstride + h * 64;
#pragma unroll
  for (int i = 0; i < 4; i++) {
    float inv = 1.f / lrow[i];
    long row = qr + lg * 4 + i;
#pragma unroll
    for (int nt = 0; nt < 4; nt++)
      yp[row * (long)y_rstride + nt * 16 + lr] = f2bf(o[nt][i] * inv);
  }
}

// ---------- layernorm (optionally + residual), f32 in, f32+bf16 out ----------
__global__ __launch_bounds__(256) void ln_k(const float* x, const float* res,
                                            const float* g, const float* bb,
                                            float* outF, u16* outB, int C) {
  __shared__ float red[8];
  long row = blockIdx.x;
  const float* xp = x + row * C;
  int i0 = threadIdx.x * 4;
  float4 v = *(const float4*)(xp + i0);
  if (res) {
    float4 r = *(const float4*)(res + row * C + i0);
    v.x += r.x; v.y += r.y; v.z += r.z; v.w += r.w;
  }
  float s = v.x + v.y + v.z + v.w;
  float sq = v.x * v.x + v.y * v.y + v.z * v.z + v.w * v.w;
#pragma unroll
  for (int off = 1; off < 64; off <<= 1) {
    s += __shfl_xor(s, off, 64);
    sq += __shfl_xor(sq, off, 64);
  }
  int w = threadIdx.x >> 6, l = threadIdx.x & 63;
  if (l == 0) { red[w] = s; red[4 + w] = sq; }
  __syncthreads();
  s = red[0] + red[1] + red[2] + red[3];
  sq = red[4] + red[5] + red[6] + red[7];
  float mean = s * (1.f / 1024.f);
  float var = sq * (1.f / 1024.f) - mean * mean;
  float rstd = rsqrtf(var + 1e-5f);
  float4 gv = *(const float4*)(g + i0);
  float4 bv = *(const float4*)(bb + i0);
  float o0 = (v.x - mean) * rstd * gv.x + bv.x;
  float o1 = (v.y - mean) * rstd * gv.y + bv.y;
  float o2 = (v.z - mean) * rstd * gv.z + bv.z;
  float o3 = (v.w - mean) * rstd * gv.w + bv.w;
  if (outF) {
    float4 ov; ov.x = o0; ov.y = o1; ov.z = o2; ov.w = o3;
    *(float4*)(outF + row * C + i0) = ov;
  }
  if (outB) {
    unsigned long long p = (unsigned long long)f2bf(o0) |
                           ((unsigned long long)f2bf(o1) << 16) |
                           ((unsigned long long)f2bf(o2) << 32) |
                           ((unsigned long long)f2bf(o3) << 48);
    *(unsigned long long*)(outB + row * C + i0) = p;
  }
}

// ---------- launcher ----------
extern "C" void kernel_launch(void* const* d_in, const int* in_sizes, int n_in,
                              void* d_out, int out_size, void* d_ws, size_t ws_size,
                              hipStream_t stream) {
  const int B = 8, N = 1024, T = 512, C = 1024, H = 16;
  const float* prev = (const float*)d_in[0];
  const float* enc = (const float*)d_in[1];
  const float* sa_w = (const float*)d_in[2];
  const float* sa_b = (const float*)d_in[3];
  const float* sa_pw = (const float*)d_in[4];
  const float* sa_pb = (const float*)d_in[5];
  const float* caq_w = (const float*)d_in[6];
  const float* caq_b = (const float*)d_in[7];
  const float* cakv_w = (const float*)d_in[8];
  const float* cakv_b = (const float*)d_in[9];
  const float* ca_pw = (const float*)d_in[10];
  const float* ca_pb = (const float*)d_in[11];
  const float* fc_w = (const float*)d_in[12];
  const float* fc_b = (const float*)d_in[13];
  const float* proj_w = (const float*)d_in[14];
  const float* proj_b = (const float*)d_in[15];
  const float* ln1_g = (const float*)d_in[16];
  const float* ln1_b = (const float*)d_in[17];
  const float* ln2_g = (const float*)d_in[18];
  const float* ln2_b = (const float*)d_in[19];
  const float* ln3_g = (const float*)d_in[20];
  const float* ln3_b = (const float*)d_in[21];

  char* ws = (char*)d_ws;
  // transposed bf16 weights (persistent this launch)
  u16* wT_sa   = (u16*)(ws + 0);               // [3072,1024]
  u16* wT_sapw = (u16*)(ws + 6291456);         // [1024,1024]
  u16* wT_caq  = (u16*)(ws + 8388608);         // [1024,1024]
  u16* wT_cakv = (u16*)(ws + 10485760);        // [2048,1024]
  u16* wT_capw = (u16*)(ws + 14680064);        // [1024,1024]
  u16* wT_fc   = (u16*)(ws + 16777216);        // [4096,1024]
  u16* wT_proj = (u16*)(ws + 25165824);        // [1024,4096]
  // activations
  u16* abf   = (u16*)(ws + 33554432);          // 16.8MB  prev bf16 -> later y2bf
  u16* encbf = (u16*)(ws + 50331648);          // 8.4MB   enc bf16 -> later vt2
  u16* qkv   = (u16*)(ws + 58720256);          // 50.3MB  qkv bf16 -> later hbf (67.1MB with vt1)
  u16* vt1   = (u16*)(ws + 109051904);         // 16.8MB
  u16* ybf   = (u16*)(ws + 125829120);         // 16.8MB  y bf16 -> later q2bf
  float* pf32 = (float*)(ws + 142606336);      // 33.6MB  gemm f32 out (reused 3x)
  float* x1f  = (float*)(ws + 176160768);      // 33.6MB  x1 f32 -> x2 f32 (in place)
  u16* x1bf  = (u16*)(ws + 209715200);         // 16.8MB  x1 bf16 -> x2 bf16
  u16* kvbf  = (u16*)(ws + 226492416);         // 16.8MB
  u16* y2bf  = abf;
  u16* vt2   = encbf;
  u16* q2bf  = ybf;
  u16* hbf   = qkv;                            // 67.1MB (qkv+vt1 regions)

  // 1. convert activations
  cvt_f32_bf16<<<8192, 256, 0, stream>>>(prev, abf, (long)B * N * C);
  cvt_f32_bf16<<<4096, 256, 0, stream>>>(enc, encbf, (long)B * T * C);
  // 2. transpose weights
  wtrans<<<dim3(96, 32), dim3(32, 8), 0, stream>>>(sa_w, wT_sa, 1024, 3072);
  wtrans<<<dim3(32, 32), dim3(32, 8), 0, stream>>>(sa_pw, wT_sapw, 1024, 1024);
  wtrans<<<dim3(32, 32), dim3(32, 8), 0, stream>>>(caq_w, wT_caq, 1024, 1024);
  wtrans<<<dim3(64, 32), dim3(32, 8), 0, stream>>>(cakv_w, wT_cakv, 1024, 2048);
  wtrans<<<dim3(32, 32), dim3(32, 8), 0, stream>>>(ca_pw, wT_capw, 1024, 1024);
  wtrans<<<dim3(128, 32), dim3(32, 8), 0, stream>>>(fc_w, wT_fc, 1024, 4096);
  wtrans<<<dim3(32, 128), dim3(32, 8), 0, stream>>>(proj_w, wT_proj, 4096, 1024);
  // 3. qkv GEMM
  gemm_bt<<<dim3(64, 24), 256, 0, stream>>>(abf, wT_sa, sa_b, nullptr, qkv, 8192, 3072, 1024, 0);
  // 4. V transpose (self)
  vtrans<<<dim3(16, 128), 256, 0, stream>>>(qkv, vt1, 1024, 3 * C, 2 * C, H);
  // 5. causal self-attention
  attn<true><<<dim3(16, 128), 256, 0, stream>>>(qkv, (long)N * 3 * C, 3 * C,
                                                qkv + C, (long)N * 3 * C, 3 * C,
                                                vt1, ybf, (long)N * C, C, N, H);
  // 6. self-attn proj
  gemm_bt<<<dim3(64, 8), 256, 0, stream>>>(ybf, wT_sapw, sa_pb, pf32, nullptr, 8192, 1024, 1024, 0);
  // 7. LN1 (no residual)
  ln_k<<<8192, 256, 0, stream>>>(pf32, nullptr, ln1_g, ln1_b, x1f, x1bf, C);
  // 8. cross q
  gemm_bt<<<dim3(64, 8), 256, 0, stream>>>(x1bf, wT_caq, caq_b, nullptr, q2bf, 8192, 1024, 1024, 0);
  // 9. cross kv
  gemm_bt<<<dim3(32, 16), 256, 0, stream>>>(encbf, wT_cakv, cakv_b, nullptr, kvbf, 4096, 2048, 1024, 0);
  // 10. V transpose (cross)
  vtrans<<<dim3(8, 128), 256, 0, stream>>>(kvbf, vt2, 512, 2 * C, C, H);
  // 11. cross-attention
  attn<false><<<dim3(16, 128), 256, 0, stream>>>(q2bf, (long)N * C, C,
                                                 kvbf, (long)T * 2 * C, 2 * C,
                                                 vt2, y2bf, (long)N * C, C, T, H);
  // 12. cross proj
  gemm_bt<<<dim3(64, 8), 256, 0, stream>>>(y2bf, wT_capw, ca_pb, pf32, nullptr, 8192, 1024, 1024, 0);
  // 13. LN2 (residual x1)
  ln_k<<<8192, 256, 0, stream>>>(pf32, x1f, ln2_g, ln2_b, x1f, x1bf, C);
  // 14. MLP fc + gelu
  gemm_bt<<<dim3(64, 32), 256, 0, stream>>>(x1bf, wT_fc, fc_b, nullptr, hbf, 8192, 4096, 1024, 1);
  // 15. MLP proj
  gemm_bt<<<dim3(64, 8), 256, 0, stream>>>(hbf, wT_proj, proj_b, pf32, nullptr, 8192, 1024, 4096, 0);
  // 16. LN3 (residual x2) -> d_out f32
  ln_k<<<8192, 256, 0, stream>>>(pf32, x1f, ln3_g, ln3_b, (float*)d_out, nullptr, C);
}

// Round 2
// 739.983 us; speedup vs baseline: 1.1900x; 1.1900x over previous
//
#include <hip/hip_runtime.h>

typedef unsigned short u16;
typedef unsigned int u32;
typedef __attribute__((ext_vector_type(8))) short short8;
typedef __attribute__((ext_vector_type(4))) float f32x4;
typedef __attribute__((ext_vector_type(16))) float f32x16;

// ---------- helpers ----------
__device__ __forceinline__ u16 f2bf(float f) {
  union { float f; unsigned int u; } v; v.f = f;
  unsigned int r = v.u + 0x7FFFu + ((v.u >> 16) & 1u);  // RNE
  return (u16)(r >> 16);
}

__device__ __forceinline__ void gload_lds16(const void* g, void* l) {
  __builtin_amdgcn_global_load_lds((const __attribute__((address_space(1))) void*)g,
                                   (__attribute__((address_space(3))) void*)l, 16, 0, 0);
}

__device__ __forceinline__ u32 cvtpk_bf16(float lo, float hi) {
  u32 r;
  asm("v_cvt_pk_bf16_f32 %0, %1, %2" : "=v"(r) : "v"(lo), "v"(hi));
  return r;
}

// new_a = {a.lo(0-31), b.lo}, new_b = {a.hi, b.hi}
__device__ __forceinline__ void plswap32(u32& a, u32& b) {
#if __has_builtin(__builtin_amdgcn_permlane32_swap)
  auto r = __builtin_amdgcn_permlane32_swap((int)a, (int)b, false, false);
  a = (u32)r[0]; b = (u32)r[1];
#else
  asm volatile("v_permlane32_swap_b32 %0, %1" : "+v"(a), "+v"(b));
#endif
}

__device__ __forceinline__ void plswapf(float& a, float& b) {
  union { float f; u32 u; } x, y; x.f = a; y.f = b;
  plswap32(x.u, y.u);
  a = x.f; b = y.f;
}

// ---------- f32 -> bf16 convert ----------
__global__ __launch_bounds__(256) void cvt_f32_bf16(const float* __restrict__ in,
                                                    u16* __restrict__ out, long n) {
  long i = ((long)blockIdx.x * 256 + threadIdx.x) * 4;
  if (i + 3 < n) {
    float4 v = *(const float4*)(in + i);
    unsigned long long p = (unsigned long long)f2bf(v.x) |
                           ((unsigned long long)f2bf(v.y) << 16) |
                           ((unsigned long long)f2bf(v.z) << 32) |
                           ((unsigned long long)f2bf(v.w) << 48);
    *(unsigned long long*)(out + i) = p;
  }
}

// ---------- weight transpose+convert: W[K,N] f32 -> WT[N,K] bf16 ----------
__global__ __launch_bounds__(256) void wtrans(const float* __restrict__ W,
                                              u16* __restrict__ WT, int K, int N) {
  __shared__ float t[32][33];
  int n0 = blockIdx.x * 32, k0 = blockIdx.y * 32;
  int tx = threadIdx.x, ty = threadIdx.y;
#pragma unroll
  for (int r = 0; r < 4; r++)
    t[ty + r * 8][tx] = W[(long)(k0 + ty + r * 8) * N + n0 + tx];
  __syncthreads();
#pragma unroll
  for (int r = 0; r < 4; r++)
    WT[(long)(n0 + ty + r * 8) * K + k0 + tx] = f2bf(t[tx][ty + r * 8]);
}

// ---------- V transpose: [b, n, head_off + h*64 + d] -> [bh][d][n] ----------
__global__ __launch_bounds__(256) void vtrans(const u16* __restrict__ src,
                                              u16* __restrict__ dst,
                                              int rows, int rstride, int head_off, int H) {
  __shared__ u16 t[64][65];
  int bh = blockIdx.y;
  int b = bh / H, h = bh % H;
  long n0 = (long)blockIdx.x * 64;
  const u16* s = src + (long)b * rows * rstride + head_off + h * 64;
  int q = threadIdx.x >> 6, ln = threadIdx.x & 63;
#pragma unroll
  for (int r = 0; r < 16; r++) {
    int nl = q * 16 + r;
    t[nl][ln] = s[(n0 + nl) * (long)rstride + ln];
  }
  __syncthreads();
  u16* d = dst + (long)bh * 64 * rows;
#pragma unroll
  for (int r = 0; r < 16; r++) {
    int dd = q * 16 + r;
    d[(long)dd * rows + n0 + ln] = t[ln][dd];
  }
}

// ---------- bf16 GEMM: C[M,N] = A[M,K] * BT[N,K]^T + bias ----------
__global__ __launch_bounds__(256) void gemm_bt(const u16* __restrict__ A,
                                               const u16* __restrict__ BT,
                                               const float* __restrict__ bias,
                                               float* __restrict__ outF,
                                               u16* __restrict__ outB,
                                               int M, int N, int K, int gelu) {
  __shared__ u16 As[128 * 32];
  __shared__ u16 Bs[128 * 32];
  const int tid = threadIdx.x;
  const int l = tid & 63;
  const int w = tid >> 6;
  const int wr = w >> 1, wc = w & 1;
  const long m0 = (long)blockIdx.x * 128, n0 = (long)blockIdx.y * 128;
  const int lr = l & 15, lg = l >> 4;

  const u16* Ag = A + (m0 + (tid >> 2)) * (long)K + (tid & 3) * 8;
  const u16* Bg = BT + (n0 + (tid >> 2)) * (long)K + (tid & 3) * 8;

  f32x4 acc[4][4];
#pragma unroll
  for (int i = 0; i < 4; i++)
#pragma unroll
    for (int j = 0; j < 4; j++) acc[i][j] = (f32x4){0.f, 0.f, 0.f, 0.f};

  for (int k0 = 0; k0 < K; k0 += 32) {
    gload_lds16(Ag + k0, As + tid * 8);
    gload_lds16(Ag + k0 + 64 * (long)K, As + 2048 + tid * 8);
    gload_lds16(Bg + k0, Bs + tid * 8);
    gload_lds16(Bg + k0 + 64 * (long)K, Bs + 2048 + tid * 8);
    __syncthreads();
    short8 a[4], b[4];
#pragma unroll
    for (int mm = 0; mm < 4; mm++)
      a[mm] = *(const short8*)&As[(wr * 64 + mm * 16 + lr) * 32 + lg * 8];
#pragma unroll
    for (int nn = 0; nn < 4; nn++)
      b[nn] = *(const short8*)&Bs[(wc * 64 + nn * 16 + lr) * 32 + lg * 8];
#pragma unroll
    for (int mm = 0; mm < 4; mm++)
#pragma unroll
      for (int nn = 0; nn < 4; nn++)
        acc[mm][nn] = __builtin_amdgcn_mfma_f32_16x16x32_bf16(a[mm], b[nn], acc[mm][nn], 0, 0, 0);
    __syncthreads();
  }

#pragma unroll
  for (int nn = 0; nn < 4; nn++) {
    const long col = n0 + wc * 64 + nn * 16 + lr;
    const float bv = bias ? bias[col] : 0.f;
#pragma unroll
    for (int mm = 0; mm < 4; mm++) {
#pragma unroll
      for (int i = 0; i < 4; i++) {
        const long row = m0 + wr * 64 + mm * 16 + lg * 4 + i;
        float v = acc[mm][nn][i] + bv;
        if (gelu) v = 0.5f * v * (1.f + erff(v * 0.70710678118654752f));
        if (outF) outF[row * N + col] = v;
        if (outB) outB[row * N + col] = f2bf(v);
      }
    }
  }
}

// ---------- flash attention, swapped-operand 32x32 (m214-style) ----------
// One wave per block (64 threads), 32 q-rows per wave, zero LDS.
// S^T = mfma(K_frag, Q_frag): lane holds P[q=lane&31][16 keys] in regs.
// O^T = mfma(VT_frag, P_frag): lane holds O^T[16 d][q=lane&31] -> m,l,alpha all lane-local.
// q: [b, n, h*64+d] via strides; k same; vt: [bh][64][Nk]; y: [b, n, h*64+d]
template <bool CAUSAL>
__global__ __launch_bounds__(64) void attn2(const u16* __restrict__ qb, long q_bstride, int q_rstride,
                                            const u16* __restrict__ kbp, long k_bstride, int k_rstride,
                                            const u16* __restrict__ vt,
                                            u16* __restrict__ yb, long y_bstride, int y_rstride,
                                            int Nk, int H) {
  const int l = threadIdx.x & 63;
  const int qi = l & 31, hi = l >> 5;
  const int bh = blockIdx.y, b = bh / H, h = bh % H;
  const int qr0 = blockIdx.x * 32;
  const u16* qp = qb + (long)b * q_bstride + h * 64;
  const u16* kp = kbp + (long)b * k_bstride + h * 64;
  const u16* vp = vt + (long)bh * 64 * Nk;
  const float CL = 0.125f * 1.44269504088896340736f;  // scale * log2(e)

  // Q fragment: B-operand, n = q = lane&31, k = d = 16*ds + 8*hi + e
  const u16* qrow = qp + (long)(qr0 + qi) * q_rstride + hi * 8;
  short8 qf0 = *(const short8*)(qrow);
  short8 qf1 = *(const short8*)(qrow + 16);
  short8 qf2 = *(const short8*)(qrow + 32);
  short8 qf3 = *(const short8*)(qrow + 48);

  f32x16 ot0, ot1;
#pragma unroll
  for (int i = 0; i < 16; i++) { ot0[i] = 0.f; ot1[i] = 0.f; }
  float m_run = -INFINITY, l_run = 0.f;

  auto body = [&](int kb0, bool dmask) __attribute__((always_inline)) {
    // QK^T (swapped): A = K-tile (m=key=lane&31, k=d)
    const u16* krow = kp + (long)(kb0 + qi) * k_rstride + hi * 8;
    short8 kf0 = *(const short8*)(krow);
    short8 kf1 = *(const short8*)(krow + 16);
    short8 kf2 = *(const short8*)(krow + 32);
    short8 kf3 = *(const short8*)(krow + 48);
    f32x16 sc;
#pragma unroll
    for (int i = 0; i < 16; i++) sc[i] = 0.f;
    sc = __builtin_amdgcn_mfma_f32_32x32x16_bf16(kf0, qf0, sc, 0, 0, 0);
    sc = __builtin_amdgcn_mfma_f32_32x32x16_bf16(kf1, qf1, sc, 0, 0, 0);
    sc = __builtin_amdgcn_mfma_f32_32x32x16_bf16(kf2, qf2, sc, 0, 0, 0);
    sc = __builtin_amdgcn_mfma_f32_32x32x16_bf16(kf3, qf3, sc, 0, 0, 0);
    // sc[r] = S[q=qi][key = kb0 + (r&3)+8*(r>>2)+4*hi]
    if (dmask) {
#pragma unroll
      for (int r = 0; r < 16; r++) {
        int key = kb0 + (r & 3) + 8 * (r >> 2) + 4 * hi;
        if (key > qr0 + qi) sc[r] = -INFINITY;
      }
    }
    // row max: 15 in-lane + pairwise lane<->lane+32 exchange
    float mx = sc[0];
#pragma unroll
    for (int r = 1; r < 16; r++) mx = fmaxf(mx, sc[r]);
    { float a = mx, bb2 = mx; plswapf(a, bb2); mx = fmaxf(a, bb2); }
    float mnew = fmaxf(m_run, mx);
    float alpha = exp2f((m_run - mnew) * CL);
    m_run = mnew;
    float p[16];
    float ssum = 0.f;
#pragma unroll
    for (int r = 0; r < 16; r++) { p[r] = exp2f((sc[r] - mnew) * CL); ssum += p[r]; }
    { float a = ssum, bb2 = ssum; plswapf(a, bb2); ssum = a + bb2; }
    l_run = l_run * alpha + ssum;
#pragma unroll
    for (int i = 0; i < 16; i++) { ot0[i] *= alpha; ot1[i] *= alpha; }
    // pack P -> bf16 fragments (B-operand of PV: k=key, n=q)
    u32 w0 = cvtpk_bf16(p[0], p[1]);
    u32 w1 = cvtpk_bf16(p[2], p[3]);
    u32 w2 = cvtpk_bf16(p[4], p[5]);
    u32 w3 = cvtpk_bf16(p[6], p[7]);
    plswap32(w0, w2);
    plswap32(w1, w3);
    u32 w4 = cvtpk_bf16(p[8], p[9]);
    u32 w5 = cvtpk_bf16(p[10], p[11]);
    u32 w6 = cvtpk_bf16(p[12], p[13]);
    u32 w7 = cvtpk_bf16(p[14], p[15]);
    plswap32(w4, w6);
    plswap32(w5, w7);
    union { u32 u[4]; short8 s; } ua0, ua1;
    ua0.u[0] = w0; ua0.u[1] = w1; ua0.u[2] = w2; ua0.u[3] = w3;
    ua1.u[0] = w4; ua1.u[1] = w5; ua1.u[2] = w6; ua1.u[3] = w7;
    short8 pa0 = ua0.s;  // keys kb0+0..15
    short8 pa1 = ua1.s;  // keys kb0+16..31
    // PV (swapped): A = V^T tile (m = d = lane&31 (+32*dt), k = key)
    const u16* vrow0 = vp + (long)qi * Nk + kb0 + hi * 8;
    const u16* vrow1 = vrow0 + 32 * (long)Nk;
    short8 va00 = *(const short8*)(vrow0);
    short8 va01 = *(const short8*)(vrow0 + 16);
    short8 va10 = *(const short8*)(vrow1);
    short8 va11 = *(const short8*)(vrow1 + 16);
    ot0 = __builtin_amdgcn_mfma_f32_32x32x16_bf16(va00, pa0, ot0, 0, 0, 0);
    ot0 = __builtin_amdgcn_mfma_f32_32x32x16_bf16(va01, pa1, ot0, 0, 0, 0);
    ot1 = __builtin_amdgcn_mfma_f32_32x32x16_bf16(va10, pa0, ot1, 0, 0, 0);
    ot1 = __builtin_amdgcn_mfma_f32_32x32x16_bf16(va11, pa1, ot1, 0, 0, 0);
  };

  const int nfull = CAUSAL ? (int)blockIdx.x : (Nk >> 5);
  for (int t0 = 0; t0 < nfull; t0++) body(t0 * 32, false);
  if (CAUSAL) body(qr0, true);

  // epilogue: O^T[d][q] -> y[row q][h*64+d]; lane holds its q's O for 32 d's
  float inv = 1.f / l_run;
  u16* yp = yb + (long)b * y_bstride + h * 64 + (long)(qr0 + qi) * y_rstride;
#pragma unroll
  for (int g = 0; g < 4; g++) {
    // ot0 regs 4g..4g+3 -> d = 8g + 4*hi + 0..3
    uint2 s0;
    s0.x = cvtpk_bf16(ot0[4 * g + 0] * inv, ot0[4 * g + 1] * inv);
    s0.y = cvtpk_bf16(ot0[4 * g + 2] * inv, ot0[4 * g + 3] * inv);
    *(uint2*)(yp + 8 * g + 4 * hi) = s0;
    uint2 s1;
    s1.x = cvtpk_bf16(ot1[4 * g + 0] * inv, ot1[4 * g + 1] * inv);
    s1.y = cvtpk_bf16(ot1[4 * g + 2] * inv, ot1[4 * g + 3] * inv);
    *(uint2*)(yp + 32 + 8 * g + 4 * hi) = s1;
  }
}

// ---------- layernorm (optionally + residual), f32 in, f32+bf16 out ----------
__global__ __launch_bounds__(256) void ln_k(const float* x, const float* res,
                                            const float* g, const float* bb,
                                            float* outF, u16* outB, int C) {
  __shared__ float red[8];
  long row = blockIdx.x;
  const float* xp = x + row * C;
  int i0 = threadIdx.x * 4;
  float4 v = *(const float4*)(xp + i0);
  if (res) {
    float4 r = *(const float4*)(res + row * C + i0);
    v.x += r.x; v.y += r.y; v.z += r.z; v.w += r.w;
  }
  float s = v.x + v.y + v.z + v.w;
  float sq = v.x * v.x + v.y * v.y + v.z * v.z + v.w * v.w;
#pragma unroll
  for (int off = 1; off < 64; off <<= 1) {
    s += __shfl_xor(s, off, 64);
    sq += __shfl_xor(sq, off, 64);
  }
  int w = threadIdx.x >> 6, l = threadIdx.x & 63;
  if (l == 0) { red[w] = s; red[4 + w] = sq; }
  __syncthreads();
  s = red[0] + red[1] + red[2] + red[3];
  sq = red[4] + red[5] + red[6] + red[7];
  float mean = s * (1.f / 1024.f);
  float var = sq * (1.f / 1024.f) - mean * mean;
  float rstd = rsqrtf(var + 1e-5f);
  float4 gv = *(const float4*)(g + i0);
  float4 bv = *(const float4*)(bb + i0);
  float o0 = (v.x - mean) * rstd * gv.x + bv.x;
  float o1 = (v.y - mean) * rstd * gv.y + bv.y;
  float o2 = (v.z - mean) * rstd * gv.z + bv.z;
  float o3 = (v.w - mean) * rstd * gv.w + bv.w;
  if (outF) {
    float4 ov; ov.x = o0; ov.y = o1; ov.z = o2; ov.w = o3;
    *(float4*)(outF + row * C + i0) = ov;
  }
  if (outB) {
    unsigned long long p = (unsigned long long)f2bf(o0) |
                           ((unsigned long long)f2bf(o1) << 16) |
                           ((unsigned long long)f2bf(o2) << 32) |
                           ((unsigned long long)f2bf(o3) << 48);
    *(unsigned long long*)(outB + row * C + i0) = p;
  }
}

// ---------- launcher ----------
extern "C" void kernel_launch(void* const* d_in, const int* in_sizes, int n_in,
                              void* d_out, int out_size, void* d_ws, size_t ws_size,
                              hipStream_t stream) {
  const int B = 8, N = 1024, T = 512, C = 1024, H = 16;
  const float* prev = (const float*)d_in[0];
  const float* enc = (const float*)d_in[1];
  const float* sa_w = (const float*)d_in[2];
  const float* sa_b = (const float*)d_in[3];
  const float* sa_pw = (const float*)d_in[4];
  const float* sa_pb = (const float*)d_in[5];
  const float* caq_w = (const float*)d_in[6];
  const float* caq_b = (const float*)d_in[7];
  const float* cakv_w = (const float*)d_in[8];
  const float* cakv_b = (const float*)d_in[9];
  const float* ca_pw = (const float*)d_in[10];
  const float* ca_pb = (const float*)d_in[11];
  const float* fc_w = (const float*)d_in[12];
  const float* fc_b = (const float*)d_in[13];
  const float* proj_w = (const float*)d_in[14];
  const float* proj_b = (const float*)d_in[15];
  const float* ln1_g = (const float*)d_in[16];
  const float* ln1_b = (const float*)d_in[17];
  const float* ln2_g = (const float*)d_in[18];
  const float* ln2_b = (const float*)d_in[19];
  const float* ln3_g = (const float*)d_in[20];
  const float* ln3_b = (const float*)d_in[21];

  char* ws = (char*)d_ws;
  u16* wT_sa   = (u16*)(ws + 0);               // [3072,1024]
  u16* wT_sapw = (u16*)(ws + 6291456);         // [1024,1024]
  u16* wT_caq  = (u16*)(ws + 8388608);         // [1024,1024]
  u16* wT_cakv = (u16*)(ws + 10485760);        // [2048,1024]
  u16* wT_capw = (u16*)(ws + 14680064);        // [1024,1024]
  u16* wT_fc   = (u16*)(ws + 16777216);        // [4096,1024]
  u16* wT_proj = (u16*)(ws + 25165824);        // [1024,4096]
  u16* abf   = (u16*)(ws + 33554432);
  u16* encbf = (u16*)(ws + 50331648);
  u16* qkv   = (u16*)(ws + 58720256);
  u16* vt1   = (u16*)(ws + 109051904);
  u16* ybf   = (u16*)(ws + 125829120);
  float* pf32 = (float*)(ws + 142606336);
  float* x1f  = (float*)(ws + 176160768);
  u16* x1bf  = (u16*)(ws + 209715200);
  u16* kvbf  = (u16*)(ws + 226492416);
  u16* y2bf  = abf;
  u16* vt2   = encbf;
  u16* q2bf  = ybf;
  u16* hbf   = qkv;

  cvt_f32_bf16<<<8192, 256, 0, stream>>>(prev, abf, (long)B * N * C);
  cvt_f32_bf16<<<4096, 256, 0, stream>>>(enc, encbf, (long)B * T * C);
  wtrans<<<dim3(96, 32), dim3(32, 8), 0, stream>>>(sa_w, wT_sa, 1024, 3072);
  wtrans<<<dim3(32, 32), dim3(32, 8), 0, stream>>>(sa_pw, wT_sapw, 1024, 1024);
  wtrans<<<dim3(32, 32), dim3(32, 8), 0, stream>>>(caq_w, wT_caq, 1024, 1024);
  wtrans<<<dim3(64, 32), dim3(32, 8), 0, stream>>>(cakv_w, wT_cakv, 1024, 2048);
  wtrans<<<dim3(32, 32), dim3(32, 8), 0, stream>>>(ca_pw, wT_capw, 1024, 1024);
  wtrans<<<dim3(128, 32), dim3(32, 8), 0, stream>>>(fc_w, wT_fc, 1024, 4096);
  wtrans<<<dim3(32, 128), dim3(32, 8), 0, stream>>>(proj_w, wT_proj, 4096, 1024);
  gemm_bt<<<dim3(64, 24), 256, 0, stream>>>(abf, wT_sa, sa_b, nullptr, qkv, 8192, 3072, 1024, 0);
  vtrans<<<dim3(16, 128), 256, 0, stream>>>(qkv, vt1, 1024, 3 * C, 2 * C, H);
  attn2<true><<<dim3(32, 128), 64, 0, stream>>>(qkv, (long)N * 3 * C, 3 * C,
                                                qkv + C, (long)N * 3 * C, 3 * C,
                                                vt1, ybf, (long)N * C, C, N, H);
  gemm_bt<<<dim3(64, 8), 256, 0, stream>>>(ybf, wT_sapw, sa_pb, pf32, nullptr, 8192, 1024, 1024, 0);
  ln_k<<<8192, 256, 0, stream>>>(pf32, nullptr, ln1_g, ln1_b, x1f, x1bf, C);
  gemm_bt<<<dim3(64, 8), 256, 0, stream>>>(x1bf, wT_caq, caq_b, nullptr, q2bf, 8192, 1024, 1024, 0);
  gemm_bt<<<dim3(32, 16), 256, 0, stream>>>(encbf, wT_cakv, cakv_b, nullptr, kvbf, 4096, 2048, 1024, 0);
  vtrans<<<dim3(8, 128), 256, 0, stream>>>(kvbf, vt2, 512, 2 * C, C, H);
  attn2<false><<<dim3(32, 128), 64, 0, stream>>>(q2bf, (long)N * C, C,
                                                 kvbf, (long)T * 2 * C, 2 * C,
                                                 vt2, y2bf, (long)N * C, C, T, H);
  gemm_bt<<<dim3(64, 8), 256, 0, stream>>>(y2bf, wT_capw, ca_pb, pf32, nullptr, 8192, 1024, 1024, 0);
  ln_k<<<8192, 256, 0, stream>>>(pf32, x1f, ln2_g, ln2_b, x1f, x1bf, C);
  gemm_bt<<<dim3(64, 32), 256, 0, stream>>>(x1bf, wT_fc, fc_b, nullptr, hbf, 8192, 4096, 1024, 1);
  gemm_bt<<<dim3(64, 8), 256, 0, stream>>>(hbf, wT_proj, proj_b, pf32, nullptr, 8192, 1024, 4096, 0);
  ln_k<<<8192, 256, 0, stream>>>(pf32, x1f, ln3_g, ln3_b, (float*)d_out, nullptr, C);
}

// Round 3
// 643.826 us; speedup vs baseline: 1.3677x; 1.1494x over previous
//
#include <hip/hip_runtime.h>

typedef unsigned short u16;
typedef unsigned int u32;
typedef __attribute__((ext_vector_type(8))) short short8;
typedef __attribute__((ext_vector_type(4))) float f32x4;
typedef __attribute__((ext_vector_type(16))) float f32x16;

// ---------- helpers ----------
__device__ __forceinline__ u16 f2bf(float f) {
  union { float f; unsigned int u; } v; v.f = f;
  unsigned int r = v.u + 0x7FFFu + ((v.u >> 16) & 1u);  // RNE
  return (u16)(r >> 16);
}

__device__ __forceinline__ void gload_lds16(const void* g, void* l) {
  __builtin_amdgcn_global_load_lds((const __attribute__((address_space(1))) void*)g,
                                   (__attribute__((address_space(3))) void*)l, 16, 0, 0);
}

__device__ __forceinline__ u32 cvtpk_bf16(float lo, float hi) {
  u32 r;
  asm("v_cvt_pk_bf16_f32 %0, %1, %2" : "=v"(r) : "v"(lo), "v"(hi));
  return r;
}

// new_a = {a.lo(0-31), b.lo}, new_b = {a.hi, b.hi}
__device__ __forceinline__ void plswap32(u32& a, u32& b) {
#if __has_builtin(__builtin_amdgcn_permlane32_swap)
  auto r = __builtin_amdgcn_permlane32_swap((int)a, (int)b, false, false);
  a = (u32)r[0]; b = (u32)r[1];
#else
  asm volatile("v_permlane32_swap_b32 %0, %1" : "+v"(a), "+v"(b));
#endif
}

__device__ __forceinline__ void plswapf(float& a, float& b) {
  union { float f; u32 u; } x, y; x.f = a; y.f = b;
  plswap32(x.u, y.u);
  a = x.f; b = y.f;
}

// ---------- f32 -> bf16 convert ----------
__global__ __launch_bounds__(256) void cvt_f32_bf16(const float* __restrict__ in,
                                                    u16* __restrict__ out, long n) {
  long i = ((long)blockIdx.x * 256 + threadIdx.x) * 4;
  if (i + 3 < n) {
    float4 v = *(const float4*)(in + i);
    unsigned long long p = (unsigned long long)f2bf(v.x) |
                           ((unsigned long long)f2bf(v.y) << 16) |
                           ((unsigned long long)f2bf(v.z) << 32) |
                           ((unsigned long long)f2bf(v.w) << 48);
    *(unsigned long long*)(out + i) = p;
  }
}

// ---------- weight transpose+convert: W[K,N] f32 -> WT[N,K] bf16 ----------
__global__ __launch_bounds__(256) void wtrans(const float* __restrict__ W,
                                              u16* __restrict__ WT, int K, int N) {
  __shared__ float t[32][33];
  int n0 = blockIdx.x * 32, k0 = blockIdx.y * 32;
  int tx = threadIdx.x, ty = threadIdx.y;
#pragma unroll
  for (int r = 0; r < 4; r++)
    t[ty + r * 8][tx] = W[(long)(k0 + ty + r * 8) * N + n0 + tx];
  __syncthreads();
#pragma unroll
  for (int r = 0; r < 4; r++)
    WT[(long)(n0 + ty + r * 8) * K + k0 + tx] = f2bf(t[tx][ty + r * 8]);
}

// ---------- V transpose: [b, n, head_off + h*64 + d] -> [bh][d][n] ----------
__global__ __launch_bounds__(256) void vtrans(const u16* __restrict__ src,
                                              u16* __restrict__ dst,
                                              int rows, int rstride, int head_off, int H) {
  __shared__ u16 t[64][65];
  int bh = blockIdx.y;
  int b = bh / H, h = bh % H;
  long n0 = (long)blockIdx.x * 64;
  const u16* s = src + (long)b * rows * rstride + head_off + h * 64;
  int q = threadIdx.x >> 6, ln = threadIdx.x & 63;
#pragma unroll
  for (int r = 0; r < 16; r++) {
    int nl = q * 16 + r;
    t[nl][ln] = s[(n0 + nl) * (long)rstride + ln];
  }
  __syncthreads();
  u16* d = dst + (long)bh * 64 * rows;
#pragma unroll
  for (int r = 0; r < 16; r++) {
    int dd = q * 16 + r;
    d[(long)dd * rows + n0 + ln] = t[ln][dd];
  }
}

// ---------- bf16 GEMM: C[M,N] = A[M,K] * BT[N,K]^T + bias ----------
__global__ __launch_bounds__(256) void gemm_bt(const u16* __restrict__ A,
                                               const u16* __restrict__ BT,
                                               const float* __restrict__ bias,
                                               float* __restrict__ outF,
                                               u16* __restrict__ outB,
                                               int M, int N, int K, int gelu) {
  __shared__ u16 As[128 * 32];
  __shared__ u16 Bs[128 * 32];
  const int tid = threadIdx.x;
  const int l = tid & 63;
  const int w = tid >> 6;
  const int wr = w >> 1, wc = w & 1;
  const long m0 = (long)blockIdx.x * 128, n0 = (long)blockIdx.y * 128;
  const int lr = l & 15, lg = l >> 4;

  const u16* Ag = A + (m0 + (tid >> 2)) * (long)K + (tid & 3) * 8;
  const u16* Bg = BT + (n0 + (tid >> 2)) * (long)K + (tid & 3) * 8;

  f32x4 acc[4][4];
#pragma unroll
  for (int i = 0; i < 4; i++)
#pragma unroll
    for (int j = 0; j < 4; j++) acc[i][j] = (f32x4){0.f, 0.f, 0.f, 0.f};

  for (int k0 = 0; k0 < K; k0 += 32) {
    gload_lds16(Ag + k0, As + tid * 8);
    gload_lds16(Ag + k0 + 64 * (long)K, As + 2048 + tid * 8);
    gload_lds16(Bg + k0, Bs + tid * 8);
    gload_lds16(Bg + k0 + 64 * (long)K, Bs + 2048 + tid * 8);
    __syncthreads();
    short8 a[4], b[4];
#pragma unroll
    for (int mm = 0; mm < 4; mm++)
      a[mm] = *(const short8*)&As[(wr * 64 + mm * 16 + lr) * 32 + lg * 8];
#pragma unroll
    for (int nn = 0; nn < 4; nn++)
      b[nn] = *(const short8*)&Bs[(wc * 64 + nn * 16 + lr) * 32 + lg * 8];
#pragma unroll
    for (int mm = 0; mm < 4; mm++)
#pragma unroll
      for (int nn = 0; nn < 4; nn++)
        acc[mm][nn] = __builtin_amdgcn_mfma_f32_16x16x32_bf16(a[mm], b[nn], acc[mm][nn], 0, 0, 0);
    __syncthreads();
  }

#pragma unroll
  for (int nn = 0; nn < 4; nn++) {
    const long col = n0 + wc * 64 + nn * 16 + lr;
    const float bv = bias ? bias[col] : 0.f;
#pragma unroll
    for (int mm = 0; mm < 4; mm++) {
#pragma unroll
      for (int i = 0; i < 4; i++) {
        const long row = m0 + wr * 64 + mm * 16 + lg * 4 + i;
        float v = acc[mm][nn][i] + bv;
        if (gelu) v = 0.5f * v * (1.f + erff(v * 0.70710678118654752f));
        if (outF) outF[row * N + col] = v;
        if (outB) outB[row * N + col] = f2bf(v);
      }
    }
  }
}

// ---------- flash attention v3: 4-wave blocks, LDS-shared K/V, double-buffered ----------
// Block: 256 threads = 4 waves; wave w owns q rows [bx*128 + 32w, +32).
// K tile [32 keys][64 d] bf16, XOR-swizzled (cb ^= row&7) -> conflict-free ds_read_b128.
// V tile [64 d][32 keys] bf16, XOR-swizzled (cb ^= d&3).
// Both staged via global_load_lds (linear LDS dest, inverse-swizzled global src).
// S^T = mfma(K,Q) swapped; O^T = mfma(V^T,P) swapped; softmax lane-local.
template <bool CAUSAL>
__global__ __launch_bounds__(256, 4) void attn3(const u16* __restrict__ qb, long q_bstride, int q_rstride,
                                                const u16* __restrict__ kbp, long k_bstride, int k_rstride,
                                                const u16* __restrict__ vt,
                                                u16* __restrict__ yb, long y_bstride, int y_rstride,
                                                int Nk, int H) {
  __shared__ __align__(16) u16 Kl[2][2048];  // [buf][row*64 + swizzled]
  __shared__ __align__(16) u16 Vl[2][2048];  // [buf][d*32 + swizzled]
  const int tid = threadIdx.x;
  const int w = tid >> 6, l = tid & 63;
  const int qi = l & 31, hi = l >> 5;

  // XCD-bijective swizzle: 8 q-blocks of one bh land in one XCD chunk
  const int nwg = gridDim.x;              // 1024 (divisible by 8)
  const int chunk = nwg >> 3;
  const int nb = (blockIdx.x & 7) * chunk + (blockIdx.x >> 3);
  const int bh = nb >> 3;
  const int bx6 = nb & 7;
  // light/heavy pairing for causal balance: {0,7,1,6,2,5,3,4}
  const int bx = (bx6 & 1) ? (7 - (bx6 >> 1)) : (bx6 >> 1);
  const int b = bh / H, h = bh % H;
  const int qr0 = bx * 128 + w * 32;
  const u16* qp = qb + (long)b * q_bstride + h * 64;
  const u16* kp = kbp + (long)b * k_bstride + h * 64;
  const u16* vp = vt + (long)bh * 64 * Nk;
  const float CL = 0.125f * 1.44269504088896340736f;  // scale * log2(e)

  // Q fragment (B-operand): n = q = lane&31, k = d
  const u16* qrow = qp + (long)(qr0 + qi) * q_rstride + hi * 8;
  short8 qf0 = *(const short8*)(qrow);
  short8 qf1 = *(const short8*)(qrow + 16);
  short8 qf2 = *(const short8*)(qrow + 32);
  short8 qf3 = *(const short8*)(qrow + 48);

  f32x16 ot0, ot1;
#pragma unroll
  for (int i = 0; i < 16; i++) { ot0[i] = 0.f; ot1[i] = 0.f; }
  float m_run = -INFINITY, l_run = 0.f;

  // staging index precompute (per thread, constant across tiles)
  const int krow_ = tid >> 3, kcb_ = (tid & 7) ^ (krow_ & 7);
  const int vrow_ = tid >> 2, vcb_ = (tid & 3) ^ (vrow_ & 3);
  const u16* kg = kp + (long)krow_ * k_rstride + kcb_ * 8;
  const u16* vg = vp + (long)vrow_ * Nk + vcb_ * 8;

  const int ntiles = CAUSAL ? (bx * 4 + 4) : (Nk >> 5);
  const int mytile = bx * 4 + w;  // last (diagonal) tile for this wave (causal)

  // prologue: stage tile 0 into buf 0
  gload_lds16(kg, &Kl[0][tid * 8]);
  gload_lds16(vg, &Vl[0][tid * 8]);
  __syncthreads();

  for (int t = 0; t < ntiles; ++t) {
    const int cur = t & 1;
    if (t + 1 < ntiles) {  // stage next tile into other buffer (overlaps compute)
      gload_lds16(kg + (t + 1) * 32 * (long)k_rstride, &Kl[cur ^ 1][tid * 8]);
      gload_lds16(vg + (t + 1) * 32, &Vl[cur ^ 1][tid * 8]);
    }
    if (!CAUSAL || t <= mytile) {
      const int kb0 = t * 32;
      const bool dmask = CAUSAL && (t == mytile);
      // K fragments from LDS (swizzled read)
      short8 kf[4];
#pragma unroll
      for (int ks = 0; ks < 4; ks++)
        kf[ks] = *(const short8*)&Kl[cur][(qi << 6) + (((2 * ks + hi) ^ (qi & 7)) << 3)];
      f32x16 sc;
#pragma unroll
      for (int i = 0; i < 16; i++) sc[i] = 0.f;
      sc = __builtin_amdgcn_mfma_f32_32x32x16_bf16(kf[0], qf0, sc, 0, 0, 0);
      sc = __builtin_amdgcn_mfma_f32_32x32x16_bf16(kf[1], qf1, sc, 0, 0, 0);
      sc = __builtin_amdgcn_mfma_f32_32x32x16_bf16(kf[2], qf2, sc, 0, 0, 0);
      sc = __builtin_amdgcn_mfma_f32_32x32x16_bf16(kf[3], qf3, sc, 0, 0, 0);
      if (dmask) {
#pragma unroll
        for (int r = 0; r < 16; r++) {
          int key = kb0 + (r & 3) + 8 * (r >> 2) + 4 * hi;
          if (key > qr0 + qi) sc[r] = -INFINITY;
        }
      }
      float mx = sc[0];
#pragma unroll
      for (int r = 1; r < 16; r++) mx = fmaxf(mx, sc[r]);
      { float a = mx, bb2 = mx; plswapf(a, bb2); mx = fmaxf(a, bb2); }
      float mnew = fmaxf(m_run, mx);
      float alpha = exp2f((m_run - mnew) * CL);
      m_run = mnew;
      float p[16];
      float ssum = 0.f;
#pragma unroll
      for (int r = 0; r < 16; r++) { p[r] = exp2f((sc[r] - mnew) * CL); ssum += p[r]; }
      { float a = ssum, bb2 = ssum; plswapf(a, bb2); ssum = a + bb2; }
      l_run = l_run * alpha + ssum;
#pragma unroll
      for (int i = 0; i < 16; i++) { ot0[i] *= alpha; ot1[i] *= alpha; }
      // pack P -> bf16 B-operand fragments
      u32 w0 = cvtpk_bf16(p[0], p[1]);
      u32 w1 = cvtpk_bf16(p[2], p[3]);
      u32 w2 = cvtpk_bf16(p[4], p[5]);
      u32 w3 = cvtpk_bf16(p[6], p[7]);
      plswap32(w0, w2);
      plswap32(w1, w3);
      u32 w4 = cvtpk_bf16(p[8], p[9]);
      u32 w5 = cvtpk_bf16(p[10], p[11]);
      u32 w6 = cvtpk_bf16(p[12], p[13]);
      u32 w7 = cvtpk_bf16(p[14], p[15]);
      plswap32(w4, w6);
      plswap32(w5, w7);
      union { u32 u[4]; short8 s; } ua0, ua1;
      ua0.u[0] = w0; ua0.u[1] = w1; ua0.u[2] = w2; ua0.u[3] = w3;
      ua1.u[0] = w4; ua1.u[1] = w5; ua1.u[2] = w6; ua1.u[3] = w7;
      // V fragments from LDS (swizzled read); A-operand rows d = qi (+32)
      short8 va00 = *(const short8*)&Vl[cur][(qi << 5) + (((hi) ^ (qi & 3)) << 3)];
      short8 va01 = *(const short8*)&Vl[cur][(qi << 5) + (((2 + hi) ^ (qi & 3)) << 3)];
      short8 va10 = *(const short8*)&Vl[cur][((qi + 32) << 5) + (((hi) ^ (qi & 3)) << 3)];
      short8 va11 = *(const short8*)&Vl[cur][((qi + 32) << 5) + (((2 + hi) ^ (qi & 3)) << 3)];
      ot0 = __builtin_amdgcn_mfma_f32_32x32x16_bf16(va00, ua0.s, ot0, 0, 0, 0);
      ot0 = __builtin_amdgcn_mfma_f32_32x32x16_bf16(va01, ua1.s, ot0, 0, 0, 0);
      ot1 = __builtin_amdgcn_mfma_f32_32x32x16_bf16(va10, ua0.s, ot1, 0, 0, 0);
      ot1 = __builtin_amdgcn_mfma_f32_32x32x16_bf16(va11, ua1.s, ot1, 0, 0, 0);
    }
    __syncthreads();
  }

  // epilogue: O^T[d][q] -> y[q][h*64+d]
  float inv = 1.f / l_run;
  u16* yp = yb + (long)b * y_bstride + h * 64 + (long)(qr0 + qi) * y_rstride;
#pragma unroll
  for (int g = 0; g < 4; g++) {
    uint2 s0;
    s0.x = cvtpk_bf16(ot0[4 * g + 0] * inv, ot0[4 * g + 1] * inv);
    s0.y = cvtpk_bf16(ot0[4 * g + 2] * inv, ot0[4 * g + 3] * inv);
    *(uint2*)(yp + 8 * g + 4 * hi) = s0;
    uint2 s1;
    s1.x = cvtpk_bf16(ot1[4 * g + 0] * inv, ot1[4 * g + 1] * inv);
    s1.y = cvtpk_bf16(ot1[4 * g + 2] * inv, ot1[4 * g + 3] * inv);
    *(uint2*)(yp + 32 + 8 * g + 4 * hi) = s1;
  }
}

// ---------- layernorm (optionally + residual), f32 in, f32+bf16 out ----------
__global__ __launch_bounds__(256) void ln_k(const float* x, const float* res,
                                            const float* g, const float* bb,
                                            float* outF, u16* outB, int C) {
  __shared__ float red[8];
  long row = blockIdx.x;
  const float* xp = x + row * C;
  int i0 = threadIdx.x * 4;
  float4 v = *(const float4*)(xp + i0);
  if (res) {
    float4 r = *(const float4*)(res + row * C + i0);
    v.x += r.x; v.y += r.y; v.z += r.z; v.w += r.w;
  }
  float s = v.x + v.y + v.z + v.w;
  float sq = v.x * v.x + v.y * v.y + v.z * v.z + v.w * v.w;
#pragma unroll
  for (int off = 1; off < 64; off <<= 1) {
    s += __shfl_xor(s, off, 64);
    sq += __shfl_xor(sq, off, 64);
  }
  int w = threadIdx.x >> 6, l = threadIdx.x & 63;
  if (l == 0) { red[w] = s; red[4 + w] = sq; }
  __syncthreads();
  s = red[0] + red[1] + red[2] + red[3];
  sq = red[4] + red[5] + red[6] + red[7];
  float mean = s * (1.f / 1024.f);
  float var = sq * (1.f / 1024.f) - mean * mean;
  float rstd = rsqrtf(var + 1e-5f);
  float4 gv = *(const float4*)(g + i0);
  float4 bv = *(const float4*)(bb + i0);
  float o0 = (v.x - mean) * rstd * gv.x + bv.x;
  float o1 = (v.y - mean) * rstd * gv.y + bv.y;
  float o2 = (v.z - mean) * rstd * gv.z + bv.z;
  float o3 = (v.w - mean) * rstd * gv.w + bv.w;
  if (outF) {
    float4 ov; ov.x = o0; ov.y = o1; ov.z = o2; ov.w = o3;
    *(float4*)(outF + row * C + i0) = ov;
  }
  if (outB) {
    unsigned long long p = (unsigned long long)f2bf(o0) |
                           ((unsigned long long)f2bf(o1) << 16) |
                           ((unsigned long long)f2bf(o2) << 32) |
                           ((unsigned long long)f2bf(o3) << 48);
    *(unsigned long long*)(outB + row * C + i0) = p;
  }
}

// ---------- launcher ----------
extern "C" void kernel_launch(void* const* d_in, const int* in_sizes, int n_in,
                              void* d_out, int out_size, void* d_ws, size_t ws_size,
                              hipStream_t stream) {
  const int B = 8, N = 1024, T = 512, C = 1024, H = 16;
  const float* prev = (const float*)d_in[0];
  const float* enc = (const float*)d_in[1];
  const float* sa_w = (const float*)d_in[2];
  const float* sa_b = (const float*)d_in[3];
  const float* sa_pw = (const float*)d_in[4];
  const float* sa_pb = (const float*)d_in[5];
  const float* caq_w = (const float*)d_in[6];
  const float* caq_b = (const float*)d_in[7];
  const float* cakv_w = (const float*)d_in[8];
  const float* cakv_b = (const float*)d_in[9];
  const float* ca_pw = (const float*)d_in[10];
  const float* ca_pb = (const float*)d_in[11];
  const float* fc_w = (const float*)d_in[12];
  const float* fc_b = (const float*)d_in[13];
  const float* proj_w = (const float*)d_in[14];
  const float* proj_b = (const float*)d_in[15];
  const float* ln1_g = (const float*)d_in[16];
  const float* ln1_b = (const float*)d_in[17];
  const float* ln2_g = (const float*)d_in[18];
  const float* ln2_b = (const float*)d_in[19];
  const float* ln3_g = (const float*)d_in[20];
  const float* ln3_b = (const float*)d_in[21];

  char* ws = (char*)d_ws;
  u16* wT_sa   = (u16*)(ws + 0);               // [3072,1024]
  u16* wT_sapw = (u16*)(ws + 6291456);         // [1024,1024]
  u16* wT_caq  = (u16*)(ws + 8388608);         // [1024,1024]
  u16* wT_cakv = (u16*)(ws + 10485760);        // [2048,1024]
  u16* wT_capw = (u16*)(ws + 14680064);        // [1024,1024]
  u16* wT_fc   = (u16*)(ws + 16777216);        // [4096,1024]
  u16* wT_proj = (u16*)(ws + 25165824);        // [1024,4096]
  u16* abf   = (u16*)(ws + 33554432);
  u16* encbf = (u16*)(ws + 50331648);
  u16* qkv   = (u16*)(ws + 58720256);
  u16* vt1   = (u16*)(ws + 109051904);
  u16* ybf   = (u16*)(ws + 125829120);
  float* pf32 = (float*)(ws + 142606336);
  float* x1f  = (float*)(ws + 176160768);
  u16* x1bf  = (u16*)(ws + 209715200);
  u16* kvbf  = (u16*)(ws + 226492416);
  u16* y2bf  = abf;
  u16* vt2   = encbf;
  u16* q2bf  = ybf;
  u16* hbf   = qkv;

  cvt_f32_bf16<<<8192, 256, 0, stream>>>(prev, abf, (long)B * N * C);
  cvt_f32_bf16<<<4096, 256, 0, stream>>>(enc, encbf, (long)B * T * C);
  wtrans<<<dim3(96, 32), dim3(32, 8), 0, stream>>>(sa_w, wT_sa, 1024, 3072);
  wtrans<<<dim3(32, 32), dim3(32, 8), 0, stream>>>(sa_pw, wT_sapw, 1024, 1024);
  wtrans<<<dim3(32, 32), dim3(32, 8), 0, stream>>>(caq_w, wT_caq, 1024, 1024);
  wtrans<<<dim3(64, 32), dim3(32, 8), 0, stream>>>(cakv_w, wT_cakv, 1024, 2048);
  wtrans<<<dim3(32, 32), dim3(32, 8), 0, stream>>>(ca_pw, wT_capw, 1024, 1024);
  wtrans<<<dim3(128, 32), dim3(32, 8), 0, stream>>>(fc_w, wT_fc, 1024, 4096);
  wtrans<<<dim3(32, 128), dim3(32, 8), 0, stream>>>(proj_w, wT_proj, 4096, 1024);
  gemm_bt<<<dim3(64, 24), 256, 0, stream>>>(abf, wT_sa, sa_b, nullptr, qkv, 8192, 3072, 1024, 0);
  vtrans<<<dim3(16, 128), 256, 0, stream>>>(qkv, vt1, 1024, 3 * C, 2 * C, H);
  attn3<true><<<dim3(1024), 256, 0, stream>>>(qkv, (long)N * 3 * C, 3 * C,
                                              qkv + C, (long)N * 3 * C, 3 * C,
                                              vt1, ybf, (long)N * C, C, N, H);
  gemm_bt<<<dim3(64, 8), 256, 0, stream>>>(ybf, wT_sapw, sa_pb, pf32, nullptr, 8192, 1024, 1024, 0);
  ln_k<<<8192, 256, 0, stream>>>(pf32, nullptr, ln1_g, ln1_b, x1f, x1bf, C);
  gemm_bt<<<dim3(64, 8), 256, 0, stream>>>(x1bf, wT_caq, caq_b, nullptr, q2bf, 8192, 1024, 1024, 0);
  gemm_bt<<<dim3(32, 16), 256, 0, stream>>>(encbf, wT_cakv, cakv_b, nullptr, kvbf, 4096, 2048, 1024, 0);
  vtrans<<<dim3(8, 128), 256, 0, stream>>>(kvbf, vt2, 512, 2 * C, C, H);
  attn3<false><<<dim3(1024), 256, 0, stream>>>(q2bf, (long)N * C, C,
                                               kvbf, (long)T * 2 * C, 2 * C,
                                               vt2, y2bf, (long)N * C, C, T, H);
  gemm_bt<<<dim3(64, 8), 256, 0, stream>>>(y2bf, wT_capw, ca_pb, pf32, nullptr, 8192, 1024, 1024, 0);
  ln_k<<<8192, 256, 0, stream>>>(pf32, x1f, ln2_g, ln2_b, x1f, x1bf, C);
  gemm_bt<<<dim3(64, 32), 256, 0, stream>>>(x1bf, wT_fc, fc_b, nullptr, hbf, 8192, 4096, 1024, 1);
  gemm_bt<<<dim3(64, 8), 256, 0, stream>>>(hbf, wT_proj, proj_b, pf32, nullptr, 8192, 1024, 4096, 0);
  ln_k<<<8192, 256, 0, stream>>>(pf32, x1f, ln3_g, ln3_b, (float*)d_out, nullptr, C);
}

// Round 4
// 642.527 us; speedup vs baseline: 1.3705x; 1.0020x over previous
//
#include <hip/hip_runtime.h>

typedef unsigned short u16;
typedef unsigned int u32;
typedef __attribute__((ext_vector_type(8))) short short8;
typedef __attribute__((ext_vector_type(4))) float f32x4;
typedef __attribute__((ext_vector_type(16))) float f32x16;

// ---------- helpers ----------
__device__ __forceinline__ u16 f2bf(float f) {
  union { float f; unsigned int u; } v; v.f = f;
  unsigned int r = v.u + 0x7FFFu + ((v.u >> 16) & 1u);  // RNE
  return (u16)(r >> 16);
}

__device__ __forceinline__ void gload_lds16(const void* g, void* l) {
  __builtin_amdgcn_global_load_lds((const __attribute__((address_space(1))) void*)g,
                                   (__attribute__((address_space(3))) void*)l, 16, 0, 0);
}

__device__ __forceinline__ u32 cvtpk_bf16(float lo, float hi) {
  u32 r;
  asm("v_cvt_pk_bf16_f32 %0, %1, %2" : "=v"(r) : "v"(lo), "v"(hi));
  return r;
}

__device__ __forceinline__ void plswap32(u32& a, u32& b) {
#if __has_builtin(__builtin_amdgcn_permlane32_swap)
  auto r = __builtin_amdgcn_permlane32_swap((int)a, (int)b, false, false);
  a = (u32)r[0]; b = (u32)r[1];
#else
  asm volatile("v_permlane32_swap_b32 %0, %1" : "+v"(a), "+v"(b));
#endif
}

__device__ __forceinline__ void plswapf(float& a, float& b) {
  union { float f; u32 u; } x, y; x.f = a; y.f = b;
  plswap32(x.u, y.u);
  a = x.f; b = y.f;
}

template <int N>
__device__ __forceinline__ void wait_vm() {
  if constexpr (N == 0) asm volatile("s_waitcnt vmcnt(0)" ::: "memory");
  else if constexpr (N == 6) asm volatile("s_waitcnt vmcnt(6)" ::: "memory");
  else if constexpr (N == 8) asm volatile("s_waitcnt vmcnt(8)" ::: "memory");
}
__device__ __forceinline__ void wait_lgkm0() {
  asm volatile("s_waitcnt lgkmcnt(0)" ::: "memory");
}

// ---------- f32 -> bf16 convert ----------
__global__ __launch_bounds__(256) void cvt_f32_bf16(const float* __restrict__ in,
                                                    u16* __restrict__ out, long n) {
  long i = ((long)blockIdx.x * 256 + threadIdx.x) * 4;
  if (i + 3 < n) {
    float4 v = *(const float4*)(in + i);
    unsigned long long p = (unsigned long long)f2bf(v.x) |
                           ((unsigned long long)f2bf(v.y) << 16) |
                           ((unsigned long long)f2bf(v.z) << 32) |
                           ((unsigned long long)f2bf(v.w) << 48);
    *(unsigned long long*)(out + i) = p;
  }
}

// ---------- weight transpose+convert: W[K,N] f32 -> WT[N,K] bf16 ----------
__global__ __launch_bounds__(256) void wtrans(const float* __restrict__ W,
                                              u16* __restrict__ WT, int K, int N) {
  __shared__ float t[32][33];
  int n0 = blockIdx.x * 32, k0 = blockIdx.y * 32;
  int tx = threadIdx.x, ty = threadIdx.y;
#pragma unroll
  for (int r = 0; r < 4; r++)
    t[ty + r * 8][tx] = W[(long)(k0 + ty + r * 8) * N + n0 + tx];
  __syncthreads();
#pragma unroll
  for (int r = 0; r < 4; r++)
    WT[(long)(n0 + ty + r * 8) * K + k0 + tx] = f2bf(t[tx][ty + r * 8]);
}

// ---------- V transpose: [b, n, head_off + h*64 + d] -> [bh][d][n] ----------
__global__ __launch_bounds__(256) void vtrans(const u16* __restrict__ src,
                                              u16* __restrict__ dst,
                                              int rows, int rstride, int head_off, int H) {
  __shared__ u16 t[64][65];
  int bh = blockIdx.y;
  int b = bh / H, h = bh % H;
  long n0 = (long)blockIdx.x * 64;
  const u16* s = src + (long)b * rows * rstride + head_off + h * 64;
  int q = threadIdx.x >> 6, ln = threadIdx.x & 63;
#pragma unroll
  for (int r = 0; r < 16; r++) {
    int nl = q * 16 + r;
    t[nl][ln] = s[(n0 + nl) * (long)rstride + ln];
  }
  __syncthreads();
  u16* d = dst + (long)bh * 64 * rows;
#pragma unroll
  for (int r = 0; r < 16; r++) {
    int dd = q * 16 + r;
    d[(long)dd * rows + n0 + ln] = t[ln][dd];
  }
}

// ---------- gemm2: C[M,N] = A[M,K] * BT[N,K]^T + bias ----------
// 8 waves (2x4), BK=64, depth-2 counted-vmcnt double buffer, T2 XOR swizzle,
// T5 setprio, T1 XCD-bijective block swizzle. BM in {256}, BN in {256,128}.
template <int BM, int BN, int GELU>
__global__ __launch_bounds__(512, 2) void gemm2(const u16* __restrict__ A,
                                                const u16* __restrict__ BT,
                                                const float* __restrict__ bias,
                                                float* __restrict__ outF,
                                                u16* __restrict__ outB,
                                                int M, int N, int K) {
  constexpr int LA = BM / 64, LB = BN / 64, L = LA + LB;
  constexpr int MR = BM / 32;  // (BM/2)/16 frags per wave, m
  constexpr int NR = BN / 64;  // (BN/4)/16 frags per wave, n
  __shared__ __align__(16) u16 As[2][BM * 64];
  __shared__ __align__(16) u16 Bs[2][BN * 64];
  const int tid = threadIdx.x;
  const int w = tid >> 6, l = tid & 63;
  const int wr = w >> 2, wc = w & 3;  // 2 (m) x 4 (n) waves
  const int lr = l & 15, lg = l >> 4;

  // T1: XCD-bijective swizzle (all grids have nwg % 8 == 0)
  const int nwg = gridDim.x * gridDim.y;
  const int lin = blockIdx.y * gridDim.x + blockIdx.x;
  const int swz = (lin & 7) * (nwg >> 3) + (lin >> 3);
  const int bx = swz % gridDim.x, by = swz / gridDim.x;
  const long m0 = (long)bx * BM, n0 = (long)by * BN;

  // stage source pointers: linear LDS dest, inverse-swizzled global source
  const u16* gA[LA];
  const u16* gB[LB];
#pragma unroll
  for (int i = 0; i < LA; i++) {
    int slot = i * 512 + tid, row = slot >> 3, sl = slot & 7;
    gA[i] = A + (m0 + row) * (long)K + ((sl ^ (row & 7)) << 3);
  }
#pragma unroll
  for (int i = 0; i < LB; i++) {
    int slot = i * 512 + tid, row = slot >> 3, sl = slot & 7;
    gB[i] = BT + (n0 + row) * (long)K + ((sl ^ (row & 7)) << 3);
  }

  f32x4 acc[MR][NR];
#pragma unroll
  for (int i = 0; i < MR; i++)
#pragma unroll
    for (int j = 0; j < NR; j++) acc[i][j] = (f32x4){0.f, 0.f, 0.f, 0.f};

  auto stage = [&](int buf, int t) {
    long ko = (long)t * 64;
#pragma unroll
    for (int i = 0; i < LA; i++) gload_lds16(gA[i] + ko, &As[buf][(i * 512 + tid) * 8]);
#pragma unroll
    for (int i = 0; i < LB; i++) gload_lds16(gB[i] + ko, &Bs[buf][(i * 512 + tid) * 8]);
  };

  const int nt = K >> 6;
  stage(0, 0);
  stage(1, 1);

  for (int t = 0; t < nt; ++t) {
    const int cur = t & 1;
    if (t + 1 < nt) wait_vm<L>(); else wait_vm<0>();
    __builtin_amdgcn_sched_barrier(0);
    __builtin_amdgcn_s_barrier();
    __builtin_amdgcn_sched_barrier(0);
    const u16* Ab = As[cur];
    const u16* Bb = Bs[cur];
    // k-chunk 0
    short8 a0[MR], b0[NR];
#pragma unroll
    for (int mm = 0; mm < MR; mm++) {
      int row = wr * (BM / 2) + mm * 16 + lr;
      a0[mm] = *(const short8*)&Ab[row * 64 + ((lg ^ (row & 7)) << 3)];
    }
#pragma unroll
    for (int nn = 0; nn < NR; nn++) {
      int row = wc * (BN / 4) + nn * 16 + lr;
      b0[nn] = *(const short8*)&Bb[row * 64 + ((lg ^ (row & 7)) << 3)];
    }
    __builtin_amdgcn_s_setprio(1);
#pragma unroll
    for (int mm = 0; mm < MR; mm++)
#pragma unroll
      for (int nn = 0; nn < NR; nn++)
        acc[mm][nn] = __builtin_amdgcn_mfma_f32_16x16x32_bf16(a0[mm], b0[nn], acc[mm][nn], 0, 0, 0);
    __builtin_amdgcn_s_setprio(0);
    // k-chunk 1
    short8 a1[MR], b1[NR];
#pragma unroll
    for (int mm = 0; mm < MR; mm++) {
      int row = wr * (BM / 2) + mm * 16 + lr;
      a1[mm] = *(const short8*)&Ab[row * 64 + (((4 + lg) ^ (row & 7)) << 3)];
    }
#pragma unroll
    for (int nn = 0; nn < NR; nn++) {
      int row = wc * (BN / 4) + nn * 16 + lr;
      b1[nn] = *(const short8*)&Bb[row * 64 + (((4 + lg) ^ (row & 7)) << 3)];
    }
    wait_lgkm0();                       // my reads of buf[cur] retired
    __builtin_amdgcn_sched_barrier(0);
    __builtin_amdgcn_s_barrier();       // all waves' reads retired
    __builtin_amdgcn_sched_barrier(0);
    if (t + 2 < nt) stage(cur, t + 2);  // overwrite buf[cur]; overlaps MFMA below
    __builtin_amdgcn_s_setprio(1);
#pragma unroll
    for (int mm = 0; mm < MR; mm++)
#pragma unroll
      for (int nn = 0; nn < NR; nn++)
        acc[mm][nn] = __builtin_amdgcn_mfma_f32_16x16x32_bf16(a1[mm], b1[nn], acc[mm][nn], 0, 0, 0);
    __builtin_amdgcn_s_setprio(0);
  }

  // epilogue
#pragma unroll
  for (int nn = 0; nn < NR; nn++) {
    const long col = n0 + wc * (BN / 4) + nn * 16 + lr;
    const float bv = bias ? bias[col] : 0.f;
#pragma unroll
    for (int mm = 0; mm < MR; mm++) {
#pragma unroll
      for (int i = 0; i < 4; i++) {
        const long row = m0 + wr * (BM / 2) + mm * 16 + lg * 4 + i;
        float v = acc[mm][nn][i] + bv;
        if (GELU) v = 0.5f * v * (1.f + erff(v * 0.70710678118654752f));
        if (outF) outF[row * N + col] = v;
        if (outB) outB[row * N + col] = f2bf(v);
      }
    }
  }
}

// ---------- flash attention v3: 4-wave blocks, LDS-shared K/V, double-buffered ----------
template <bool CAUSAL>
__global__ __launch_bounds__(256, 4) void attn3(const u16* __restrict__ qb, long q_bstride, int q_rstride,
                                                const u16* __restrict__ kbp, long k_bstride, int k_rstride,
                                                const u16* __restrict__ vt,
                                                u16* __restrict__ yb, long y_bstride, int y_rstride,
                                                int Nk, int H) {
  __shared__ __align__(16) u16 Kl[2][2048];
  __shared__ __align__(16) u16 Vl[2][2048];
  const int tid = threadIdx.x;
  const int w = tid >> 6, l = tid & 63;
  const int qi = l & 31, hi = l >> 5;

  const int nwg = gridDim.x;
  const int chunk = nwg >> 3;
  const int nb = (blockIdx.x & 7) * chunk + (blockIdx.x >> 3);
  const int bh = nb >> 3;
  const int bx6 = nb & 7;
  const int bx = (bx6 & 1) ? (7 - (bx6 >> 1)) : (bx6 >> 1);
  const int b = bh / H, h = bh % H;
  const int qr0 = bx * 128 + w * 32;
  const u16* qp = qb + (long)b * q_bstride + h * 64;
  const u16* kp = kbp + (long)b * k_bstride + h * 64;
  const u16* vp = vt + (long)bh * 64 * Nk;
  const float CL = 0.125f * 1.44269504088896340736f;

  const u16* qrow = qp + (long)(qr0 + qi) * q_rstride + hi * 8;
  short8 qf0 = *(const short8*)(qrow);
  short8 qf1 = *(const short8*)(qrow + 16);
  short8 qf2 = *(const short8*)(qrow + 32);
  short8 qf3 = *(const short8*)(qrow + 48);

  f32x16 ot0, ot1;
#pragma unroll
  for (int i = 0; i < 16; i++) { ot0[i] = 0.f; ot1[i] = 0.f; }
  float m_run = -INFINITY, l_run = 0.f;

  const int krow_ = tid >> 3, kcb_ = (tid & 7) ^ (krow_ & 7);
  const int vrow_ = tid >> 2, vcb_ = (tid & 3) ^ (vrow_ & 3);
  const u16* kg = kp + (long)krow_ * k_rstride + kcb_ * 8;
  const u16* vg = vp + (long)vrow_ * Nk + vcb_ * 8;

  const int ntiles = CAUSAL ? (bx * 4 + 4) : (Nk >> 5);
  const int mytile = bx * 4 + w;

  gload_lds16(kg, &Kl[0][tid * 8]);
  gload_lds16(vg, &Vl[0][tid * 8]);
  __syncthreads();

  for (int t = 0; t < ntiles; ++t) {
    const int cur = t & 1;
    if (t + 1 < ntiles) {
      gload_lds16(kg + (t + 1) * 32 * (long)k_rstride, &Kl[cur ^ 1][tid * 8]);
      gload_lds16(vg + (t + 1) * 32, &Vl[cur ^ 1][tid * 8]);
    }
    if (!CAUSAL || t <= mytile) {
      const int kb0 = t * 32;
      const bool dmask = CAUSAL && (t == mytile);
      short8 kf[4];
#pragma unroll
      for (int ks = 0; ks < 4; ks++)
        kf[ks] = *(const short8*)&Kl[cur][(qi << 6) + (((2 * ks + hi) ^ (qi & 7)) << 3)];
      f32x16 sc;
#pragma unroll
      for (int i = 0; i < 16; i++) sc[i] = 0.f;
      sc = __builtin_amdgcn_mfma_f32_32x32x16_bf16(kf[0], qf0, sc, 0, 0, 0);
      sc = __builtin_amdgcn_mfma_f32_32x32x16_bf16(kf[1], qf1, sc, 0, 0, 0);
      sc = __builtin_amdgcn_mfma_f32_32x32x16_bf16(kf[2], qf2, sc, 0, 0, 0);
      sc = __builtin_amdgcn_mfma_f32_32x32x16_bf16(kf[3], qf3, sc, 0, 0, 0);
      if (dmask) {
#pragma unroll
        for (int r = 0; r < 16; r++) {
          int key = kb0 + (r & 3) + 8 * (r >> 2) + 4 * hi;
          if (key > qr0 + qi) sc[r] = -INFINITY;
        }
      }
      float mx = sc[0];
#pragma unroll
      for (int r = 1; r < 16; r++) mx = fmaxf(mx, sc[r]);
      { float a = mx, bb2 = mx; plswapf(a, bb2); mx = fmaxf(a, bb2); }
      float mnew = fmaxf(m_run, mx);
      float alpha = exp2f((m_run - mnew) * CL);
      m_run = mnew;
      float p[16];
      float ssum = 0.f;
#pragma unroll
      for (int r = 0; r < 16; r++) { p[r] = exp2f((sc[r] - mnew) * CL); ssum += p[r]; }
      { float a = ssum, bb2 = ssum; plswapf(a, bb2); ssum = a + bb2; }
      l_run = l_run * alpha + ssum;
#pragma unroll
      for (int i = 0; i < 16; i++) { ot0[i] *= alpha; ot1[i] *= alpha; }
      u32 w0 = cvtpk_bf16(p[0], p[1]);
      u32 w1 = cvtpk_bf16(p[2], p[3]);
      u32 w2 = cvtpk_bf16(p[4], p[5]);
      u32 w3 = cvtpk_bf16(p[6], p[7]);
      plswap32(w0, w2);
      plswap32(w1, w3);
      u32 w4 = cvtpk_bf16(p[8], p[9]);
      u32 w5 = cvtpk_bf16(p[10], p[11]);
      u32 w6 = cvtpk_bf16(p[12], p[13]);
      u32 w7 = cvtpk_bf16(p[14], p[15]);
      plswap32(w4, w6);
      plswap32(w5, w7);
      union { u32 u[4]; short8 s; } ua0, ua1;
      ua0.u[0] = w0; ua0.u[1] = w1; ua0.u[2] = w2; ua0.u[3] = w3;
      ua1.u[0] = w4; ua1.u[1] = w5; ua1.u[2] = w6; ua1.u[3] = w7;
      short8 va00 = *(const short8*)&Vl[cur][(qi << 5) + (((hi) ^ (qi & 3)) << 3)];
      short8 va01 = *(const short8*)&Vl[cur][(qi << 5) + (((2 + hi) ^ (qi & 3)) << 3)];
      short8 va10 = *(const short8*)&Vl[cur][((qi + 32) << 5) + (((hi) ^ (qi & 3)) << 3)];
      short8 va11 = *(const short8*)&Vl[cur][((qi + 32) << 5) + (((2 + hi) ^ (qi & 3)) << 3)];
      ot0 = __builtin_amdgcn_mfma_f32_32x32x16_bf16(va00, ua0.s, ot0, 0, 0, 0);
      ot0 = __builtin_amdgcn_mfma_f32_32x32x16_bf16(va01, ua1.s, ot0, 0, 0, 0);
      ot1 = __builtin_amdgcn_mfma_f32_32x32x16_bf16(va10, ua0.s, ot1, 0, 0, 0);
      ot1 = __builtin_amdgcn_mfma_f32_32x32x16_bf16(va11, ua1.s, ot1, 0, 0, 0);
    }
    __syncthreads();
  }

  float inv = 1.f / l_run;
  u16* yp = yb + (long)b * y_bstride + h * 64 + (long)(qr0 + qi) * y_rstride;
#pragma unroll
  for (int g = 0; g < 4; g++) {
    uint2 s0;
    s0.x = cvtpk_bf16(ot0[4 * g + 0] * inv, ot0[4 * g + 1] * inv);
    s0.y = cvtpk_bf16(ot0[4 * g + 2] * inv, ot0[4 * g + 3] * inv);
    *(uint2*)(yp + 8 * g + 4 * hi) = s0;
    uint2 s1;
    s1.x = cvtpk_bf16(ot1[4 * g + 0] * inv, ot1[4 * g + 1] * inv);
    s1.y = cvtpk_bf16(ot1[4 * g + 2] * inv, ot1[4 * g + 3] * inv);
    *(uint2*)(yp + 32 + 8 * g + 4 * hi) = s1;
  }
}

// ---------- layernorm (optionally + residual), f32 in, f32+bf16 out ----------
__global__ __launch_bounds__(256) void ln_k(const float* x, const float* res,
                                            const float* g, const float* bb,
                                            float* outF, u16* outB, int C) {
  __shared__ float red[8];
  long row = blockIdx.x;
  const float* xp = x + row * C;
  int i0 = threadIdx.x * 4;
  float4 v = *(const float4*)(xp + i0);
  if (res) {
    float4 r = *(const float4*)(res + row * C + i0);
    v.x += r.x; v.y += r.y; v.z += r.z; v.w += r.w;
  }
  float s = v.x + v.y + v.z + v.w;
  float sq = v.x * v.x + v.y * v.y + v.z * v.z + v.w * v.w;
#pragma unroll
  for (int off = 1; off < 64; off <<= 1) {
    s += __shfl_xor(s, off, 64);
    sq += __shfl_xor(sq, off, 64);
  }
  int w = threadIdx.x >> 6, l = threadIdx.x & 63;
  if (l == 0) { red[w] = s; red[4 + w] = sq; }
  __syncthreads();
  s = red[0] + red[1] + red[2] + red[3];
  sq = red[4] + red[5] + red[6] + red[7];
  float mean = s * (1.f / 1024.f);
  float var = sq * (1.f / 1024.f) - mean * mean;
  float rstd = rsqrtf(var + 1e-5f);
  float4 gv = *(const float4*)(g + i0);
  float4 bv = *(const float4*)(bb + i0);
  float o0 = (v.x - mean) * rstd * gv.x + bv.x;
  float o1 = (v.y - mean) * rstd * gv.y + bv.y;
  float o2 = (v.z - mean) * rstd * gv.z + bv.z;
  float o3 = (v.w - mean) * rstd * gv.w + bv.w;
  if (outF) {
    float4 ov; ov.x = o0; ov.y = o1; ov.z = o2; ov.w = o3;
    *(float4*)(outF + row * C + i0) = ov;
  }
  if (outB) {
    unsigned long long p = (unsigned long long)f2bf(o0) |
                           ((unsigned long long)f2bf(o1) << 16) |
                           ((unsigned long long)f2bf(o2) << 32) |
                           ((unsigned long long)f2bf(o3) << 48);
    *(unsigned long long*)(outB + row * C + i0) = p;
  }
}

// ---------- launcher ----------
extern "C" void kernel_launch(void* const* d_in, const int* in_sizes, int n_in,
                              void* d_out, int out_size, void* d_ws, size_t ws_size,
                              hipStream_t stream) {
  const int B = 8, N = 1024, T = 512, C = 1024, H = 16;
  const float* prev = (const float*)d_in[0];
  const float* enc = (const float*)d_in[1];
  const float* sa_w = (const float*)d_in[2];
  const float* sa_b = (const float*)d_in[3];
  const float* sa_pw = (const float*)d_in[4];
  const float* sa_pb = (const float*)d_in[5];
  const float* caq_w = (const float*)d_in[6];
  const float* caq_b = (const float*)d_in[7];
  const float* cakv_w = (const float*)d_in[8];
  const float* cakv_b = (const float*)d_in[9];
  const float* ca_pw = (const float*)d_in[10];
  const float* ca_pb = (const float*)d_in[11];
  const float* fc_w = (const float*)d_in[12];
  const float* fc_b = (const float*)d_in[13];
  const float* proj_w = (const float*)d_in[14];
  const float* proj_b = (const float*)d_in[15];
  const float* ln1_g = (const float*)d_in[16];
  const float* ln1_b = (const float*)d_in[17];
  const float* ln2_g = (const float*)d_in[18];
  const float* ln2_b = (const float*)d_in[19];
  const float* ln3_g = (const float*)d_in[20];
  const float* ln3_b = (const float*)d_in[21];

  char* ws = (char*)d_ws;
  u16* wT_sa   = (u16*)(ws + 0);               // [3072,1024]
  u16* wT_sapw = (u16*)(ws + 6291456);         // [1024,1024]
  u16* wT_caq  = (u16*)(ws + 8388608);         // [1024,1024]
  u16* wT_cakv = (u16*)(ws + 10485760);        // [2048,1024]
  u16* wT_capw = (u16*)(ws + 14680064);        // [1024,1024]
  u16* wT_fc   = (u16*)(ws + 16777216);        // [4096,1024]
  u16* wT_proj = (u16*)(ws + 25165824);        // [1024,4096]
  u16* abf   = (u16*)(ws + 33554432);
  u16* encbf = (u16*)(ws + 50331648);
  u16* qkv   = (u16*)(ws + 58720256);
  u16* vt1   = (u16*)(ws + 109051904);
  u16* ybf   = (u16*)(ws + 125829120);
  float* pf32 = (float*)(ws + 142606336);
  float* x1f  = (float*)(ws + 176160768);
  u16* x1bf  = (u16*)(ws + 209715200);
  u16* kvbf  = (u16*)(ws + 226492416);
  u16* y2bf  = abf;
  u16* vt2   = encbf;
  u16* q2bf  = ybf;
  u16* hbf   = qkv;

  cvt_f32_bf16<<<8192, 256, 0, stream>>>(prev, abf, (long)B * N * C);
  cvt_f32_bf16<<<4096, 256, 0, stream>>>(enc, encbf, (long)B * T * C);
  wtrans<<<dim3(96, 32), dim3(32, 8), 0, stream>>>(sa_w, wT_sa, 1024, 3072);
  wtrans<<<dim3(32, 32), dim3(32, 8), 0, stream>>>(sa_pw, wT_sapw, 1024, 1024);
  wtrans<<<dim3(32, 32), dim3(32, 8), 0, stream>>>(caq_w, wT_caq, 1024, 1024);
  wtrans<<<dim3(64, 32), dim3(32, 8), 0, stream>>>(cakv_w, wT_cakv, 1024, 2048);
  wtrans<<<dim3(32, 32), dim3(32, 8), 0, stream>>>(ca_pw, wT_capw, 1024, 1024);
  wtrans<<<dim3(128, 32), dim3(32, 8), 0, stream>>>(fc_w, wT_fc, 1024, 4096);
  wtrans<<<dim3(32, 128), dim3(32, 8), 0, stream>>>(proj_w, wT_proj, 4096, 1024);
  // qkv
  gemm2<256, 128, 0><<<dim3(32, 24), 512, 0, stream>>>(abf, wT_sa, sa_b, nullptr, qkv, 8192, 3072, 1024);
  vtrans<<<dim3(16, 128), 256, 0, stream>>>(qkv, vt1, 1024, 3 * C, 2 * C, H);
  attn3<true><<<dim3(1024), 256, 0, stream>>>(qkv, (long)N * 3 * C, 3 * C,
                                              qkv + C, (long)N * 3 * C, 3 * C,
                                              vt1, ybf, (long)N * C, C, N, H);
  gemm2<256, 128, 0><<<dim3(32, 8), 512, 0, stream>>>(ybf, wT_sapw, sa_pb, pf32, nullptr, 8192, 1024, 1024);
  ln_k<<<8192, 256, 0, stream>>>(pf32, nullptr, ln1_g, ln1_b, x1f, x1bf, C);
  gemm2<256, 128, 0><<<dim3(32, 8), 512, 0, stream>>>(x1bf, wT_caq, caq_b, nullptr, q2bf, 8192, 1024, 1024);
  gemm2<256, 128, 0><<<dim3(16, 16), 512, 0, stream>>>(encbf, wT_cakv, cakv_b, nullptr, kvbf, 4096, 2048, 1024);
  vtrans<<<dim3(8, 128), 256, 0, stream>>>(kvbf, vt2, 512, 2 * C, C, H);
  attn3<false><<<dim3(1024), 256, 0, stream>>>(q2bf, (long)N * C, C,
                                               kvbf, (long)T * 2 * C, 2 * C,
                                               vt2, y2bf, (long)N * C, C, T, H);
  gemm2<256, 128, 0><<<dim3(32, 8), 512, 0, stream>>>(y2bf, wT_capw, ca_pb, pf32, nullptr, 8192, 1024, 1024);
  ln_k<<<8192, 256, 0, stream>>>(pf32, x1f, ln2_g, ln2_b, x1f, x1bf, C);
  gemm2<256, 256, 1><<<dim3(32, 16), 512, 0, stream>>>(x1bf, wT_fc, fc_b, nullptr, hbf, 8192, 4096, 1024);
  gemm2<256, 128, 0><<<dim3(32, 8), 512, 0, stream>>>(hbf, wT_proj, proj_b, pf32, nullptr, 8192, 1024, 4096);
  ln_k<<<8192, 256, 0, stream>>>(pf32, x1f, ln3_g, ln3_b, (float*)d_out, nullptr, C);
}

// Round 5
// 595.939 us; speedup vs baseline: 1.4776x; 1.0782x over previous
//
#include <hip/hip_runtime.h>

typedef unsigned short u16;
typedef unsigned int u32;
typedef __attribute__((ext_vector_type(8))) short short8;
typedef __attribute__((ext_vector_type(4))) float f32x4;
typedef __attribute__((ext_vector_type(16))) float f32x16;

// ---------- helpers ----------
__device__ __forceinline__ u16 f2bf(float f) {
  union { float f; unsigned int u; } v; v.f = f;
  unsigned int r = v.u + 0x7FFFu + ((v.u >> 16) & 1u);  // RNE
  return (u16)(r >> 16);
}

__device__ __forceinline__ void gload_lds16(const void* g, void* l) {
  __builtin_amdgcn_global_load_lds((const __attribute__((address_space(1))) void*)g,
                                   (__attribute__((address_space(3))) void*)l, 16, 0, 0);
}

__device__ __forceinline__ u32 cvtpk_bf16(float lo, float hi) {
  u32 r;
  asm("v_cvt_pk_bf16_f32 %0, %1, %2" : "=v"(r) : "v"(lo), "v"(hi));
  return r;
}

__device__ __forceinline__ void plswap32(u32& a, u32& b) {
#if __has_builtin(__builtin_amdgcn_permlane32_swap)
  auto r = __builtin_amdgcn_permlane32_swap((int)a, (int)b, false, false);
  a = (u32)r[0]; b = (u32)r[1];
#else
  asm volatile("v_permlane32_swap_b32 %0, %1" : "+v"(a), "+v"(b));
#endif
}

__device__ __forceinline__ void plswapf(float& a, float& b) {
  union { float f; u32 u; } x, y; x.f = a; y.f = b;
  plswap32(x.u, y.u);
  a = x.f; b = y.f;
}

template <int N>
__device__ __forceinline__ void wait_vm() {
  if constexpr (N == 0) asm volatile("s_waitcnt vmcnt(0)" ::: "memory");
  else if constexpr (N == 3) asm volatile("s_waitcnt vmcnt(3)" ::: "memory");
  else if constexpr (N == 4) asm volatile("s_waitcnt vmcnt(4)" ::: "memory");
  else if constexpr (N == 6) asm volatile("s_waitcnt vmcnt(6)" ::: "memory");
  else if constexpr (N == 8) asm volatile("s_waitcnt vmcnt(8)" ::: "memory");
}
__device__ __forceinline__ void wait_lgkm0() {
  asm volatile("s_waitcnt lgkmcnt(0)" ::: "memory");
}
#define SBAR() __builtin_amdgcn_sched_barrier(0)

// ---------- f32 -> bf16 convert ----------
__global__ __launch_bounds__(256) void cvt_f32_bf16(const float* __restrict__ in,
                                                    u16* __restrict__ out, long n) {
  long i = ((long)blockIdx.x * 256 + threadIdx.x) * 4;
  if (i + 3 < n) {
    float4 v = *(const float4*)(in + i);
    unsigned long long p = (unsigned long long)f2bf(v.x) |
                           ((unsigned long long)f2bf(v.y) << 16) |
                           ((unsigned long long)f2bf(v.z) << 32) |
                           ((unsigned long long)f2bf(v.w) << 48);
    *(unsigned long long*)(out + i) = p;
  }
}

// ---------- weight transpose+convert: W[K,N] f32 -> WT[N,K] bf16 ----------
__global__ __launch_bounds__(256) void wtrans(const float* __restrict__ W,
                                              u16* __restrict__ WT, int K, int N) {
  __shared__ float t[32][33];
  int n0 = blockIdx.x * 32, k0 = blockIdx.y * 32;
  int tx = threadIdx.x, ty = threadIdx.y;
#pragma unroll
  for (int r = 0; r < 4; r++)
    t[ty + r * 8][tx] = W[(long)(k0 + ty + r * 8) * N + n0 + tx];
  __syncthreads();
#pragma unroll
  for (int r = 0; r < 4; r++)
    WT[(long)(n0 + ty + r * 8) * K + k0 + tx] = f2bf(t[tx][ty + r * 8]);
}

// ---------- V transpose: [b, n, head_off + h*64 + d] -> [bh][d][n] ----------
__global__ __launch_bounds__(256) void vtrans(const u16* __restrict__ src,
                                              u16* __restrict__ dst,
                                              int rows, int rstride, int head_off, int H) {
  __shared__ u16 t[64][65];
  int bh = blockIdx.y;
  int b = bh / H, h = bh % H;
  long n0 = (long)blockIdx.x * 64;
  const u16* s = src + (long)b * rows * rstride + head_off + h * 64;
  int q = threadIdx.x >> 6, ln = threadIdx.x & 63;
#pragma unroll
  for (int r = 0; r < 16; r++) {
    int nl = q * 16 + r;
    t[nl][ln] = s[(n0 + nl) * (long)rstride + ln];
  }
  __syncthreads();
  u16* d = dst + (long)bh * 64 * rows;
#pragma unroll
  for (int r = 0; r < 16; r++) {
    int dd = q * 16 + r;
    d[(long)dd * rows + n0 + ln] = t[ln][dd];
  }
}

// ---------- gemm3: 4-phase/K-tile counted-vmcnt pipeline ----------
// BM=256, BK=64 (2 K-halves of 32), 8 waves (2m x 4n), per-wave out 128 x BN/4.
// LDS [2 dbuf][2 kh][rows*32], slot-rotated swizzle (2-way, free).
// Stage: 1 half-unit per phase, 5-6 phases of prefetch distance.
// vmcnt ledger (loads/half-unit: A=2, B=BLB): steady 4+2*BLB at ph0/ph2;
// last tile: 2+BLB at ph0, 0 at ph2. XCD mapping: bx-groups (A-slab L2-resident).
template <int BN, int GELU>
__global__ __launch_bounds__(512, 1) void gemm3(const u16* __restrict__ A,
                                                const u16* __restrict__ BT,
                                                const float* __restrict__ bias,
                                                float* __restrict__ outF,
                                                u16* __restrict__ outB,
                                                int M, int N, int K) {
  constexpr int BM = 256;
  constexpr int NR = BN / 64;       // n frags per wave
  constexpr int BLB = BN / 128;     // B gload_lds per thread per half-unit
  constexpr int VMS = 4 + 2 * BLB;  // steady vmcnt
  constexpr int VML = 2 + BLB;      // last-tile ph0
  __shared__ __align__(16) u16 Al[2][2][BM * 32];
  __shared__ __align__(16) u16 Bl[2][2][BN * 32];
  const int tid = threadIdx.x;
  const int w = tid >> 6, l = tid & 63;
  const int wr = w >> 2, wc = w & 3;
  const int lr = l & 15, lg = l >> 4;

  // XCD mapping: each XCD owns nx/8 contiguous bx (A slabs), streams by
  const int nx = M >> 8;
  const int gpx = nx >> 3;
  const int hgt = blockIdx.x;
  const int xcd = hgt & 7, j = hgt >> 3;
  const int bx = xcd * gpx + (j % gpx);
  const int by = j / gpx;
  const long m0 = (long)bx * BM, n0 = (long)by * BN;

  const int nt = K >> 6;

  // stage source bases (inverse-swizzled global, linear LDS dest)
  const u16* baseA[2];
#pragma unroll
  for (int rr = 0; rr < 2; rr++) {
    int e = rr * 512 + tid, row = e >> 2;
    int kk = ((e & 3) - (row >> 1)) & 3;
    baseA[rr] = A + (m0 + row) * (long)K + kk * 8;
  }
  const u16* baseB[BLB];
#pragma unroll
  for (int rr = 0; rr < BLB; rr++) {
    int e = rr * 512 + tid, row = e >> 2;
    int kk = ((e & 3) - (row >> 1)) & 3;
    baseB[rr] = BT + (n0 + row) * (long)K + kk * 8;
  }

  auto stA = [&](int buf, int kh, int t) {
    if (t < nt) {
#pragma unroll
      for (int rr = 0; rr < 2; rr++)
        gload_lds16(baseA[rr] + (long)t * 64 + kh * 32, &Al[buf][kh][(rr * 512 + tid) * 8]);
    }
  };
  auto stB = [&](int buf, int kh, int t) {
    if (t < nt) {
#pragma unroll
      for (int rr = 0; rr < BLB; rr++)
        gload_lds16(baseB[rr] + (long)t * 64 + kh * 32, &Bl[buf][kh][(rr * 512 + tid) * 8]);
    }
  };

  f32x4 acc[8][NR];
#pragma unroll
  for (int i = 0; i < 8; i++)
#pragma unroll
    for (int nn = 0; nn < NR; nn++) acc[i][nn] = (f32x4){0.f, 0.f, 0.f, 0.f};

  // prologue: A0(0) B0(0) A1(0) B1(0) A0(1) B0(1)
  stA(0, 0, 0); stB(0, 0, 0); stA(0, 1, 0); stB(0, 1, 0); stA(1, 0, 1); stB(1, 0, 1);

  for (int t = 0; t < nt; ++t) {
    const int bt = t & 1, nb = bt ^ 1;
    const bool lastt = (t == nt - 1);
    const u16* A0 = &Al[bt][0][0];
    const u16* A1 = &Al[bt][1][0];
    const u16* B0 = &Bl[bt][0][0];
    const u16* B1 = &Bl[bt][1][0];

    // ===== phase 0 (kc=0, mm 0-3) =====
    if (lastt) wait_vm<VML>(); else wait_vm<VMS>();
    SBAR(); __builtin_amdgcn_s_barrier(); SBAR();
    short8 bf[NR], af[4];
#pragma unroll
    for (int nn = 0; nn < NR; nn++) {
      int row = wc * (BN / 4) + nn * 16 + lr;
      bf[nn] = *(const short8*)&B0[row * 32 + (((lg + (row >> 1)) & 3) << 3)];
    }
#pragma unroll
    for (int mm = 0; mm < 4; mm++) {
      int row = wr * 128 + mm * 16 + lr;
      af[mm] = *(const short8*)&A0[row * 32 + (((lg + (row >> 1)) & 3) << 3)];
    }
    stA(nb, 1, t + 1);
    wait_lgkm0(); SBAR();
    __builtin_amdgcn_s_setprio(1);
#pragma unroll
    for (int mm = 0; mm < 4; mm++)
#pragma unroll
      for (int nn = 0; nn < NR; nn++)
        acc[mm][nn] = __builtin_amdgcn_mfma_f32_16x16x32_bf16(af[mm], bf[nn], acc[mm][nn], 0, 0, 0);
    __builtin_amdgcn_s_setprio(0);
    SBAR(); __builtin_amdgcn_s_barrier(); SBAR();

    // ===== phase 1 (kc=0, mm 4-7) =====
#pragma unroll
    for (int mm = 0; mm < 4; mm++) {
      int row = wr * 128 + (mm + 4) * 16 + lr;
      af[mm] = *(const short8*)&A0[row * 32 + (((lg + (row >> 1)) & 3) << 3)];
    }
    stB(nb, 1, t + 1);
    wait_lgkm0(); SBAR();
    __builtin_amdgcn_s_setprio(1);
#pragma unroll
    for (int mm = 0; mm < 4; mm++)
#pragma unroll
      for (int nn = 0; nn < NR; nn++)
        acc[mm + 4][nn] = __builtin_amdgcn_mfma_f32_16x16x32_bf16(af[mm], bf[nn], acc[mm + 4][nn], 0, 0, 0);
    __builtin_amdgcn_s_setprio(0);
    SBAR(); __builtin_amdgcn_s_barrier(); SBAR();

    // ===== phase 2 (kc=1, mm 0-3) =====
    if (lastt) wait_vm<0>(); else wait_vm<VMS>();
    SBAR(); __builtin_amdgcn_s_barrier(); SBAR();
#pragma unroll
    for (int nn = 0; nn < NR; nn++) {
      int row = wc * (BN / 4) + nn * 16 + lr;
      bf[nn] = *(const short8*)&B1[row * 32 + (((lg + (row >> 1)) & 3) << 3)];
    }
#pragma unroll
    for (int mm = 0; mm < 4; mm++) {
      int row = wr * 128 + mm * 16 + lr;
      af[mm] = *(const short8*)&A1[row * 32 + (((lg + (row >> 1)) & 3) << 3)];
    }
    stA(bt, 0, t + 2);
    wait_lgkm0(); SBAR();
    __builtin_amdgcn_s_setprio(1);
#pragma unroll
    for (int mm = 0; mm < 4; mm++)
#pragma unroll
      for (int nn = 0; nn < NR; nn++)
        acc[mm][nn] = __builtin_amdgcn_mfma_f32_16x16x32_bf16(af[mm], bf[nn], acc[mm][nn], 0, 0, 0);
    __builtin_amdgcn_s_setprio(0);
    SBAR(); __builtin_amdgcn_s_barrier(); SBAR();

    // ===== phase 3 (kc=1, mm 4-7) =====
#pragma unroll
    for (int mm = 0; mm < 4; mm++) {
      int row = wr * 128 + (mm + 4) * 16 + lr;
      af[mm] = *(const short8*)&A1[row * 32 + (((lg + (row >> 1)) & 3) << 3)];
    }
    stB(bt, 0, t + 2);
    wait_lgkm0(); SBAR();
    __builtin_amdgcn_s_setprio(1);
#pragma unroll
    for (int mm = 0; mm < 4; mm++)
#pragma unroll
      for (int nn = 0; nn < NR; nn++)
        acc[mm + 4][nn] = __builtin_amdgcn_mfma_f32_16x16x32_bf16(af[mm], bf[nn], acc[mm + 4][nn], 0, 0, 0);
    __builtin_amdgcn_s_setprio(0);
    SBAR(); __builtin_amdgcn_s_barrier(); SBAR();
  }

  // epilogue
#pragma unroll
  for (int nn = 0; nn < NR; nn++) {
    const long col = n0 + wc * (BN / 4) + nn * 16 + lr;
    const float bv = bias ? bias[col] : 0.f;
#pragma unroll
    for (int mm = 0; mm < 8; mm++) {
#pragma unroll
      for (int i = 0; i < 4; i++) {
        const long row = m0 + wr * 128 + mm * 16 + lg * 4 + i;
        float v = acc[mm][nn][i] + bv;
        if (GELU) v = 0.5f * v * (1.f + erff(v * 0.70710678118654752f));
        if (outF) outF[row * N + col] = v;
        if (outB) outB[row * N + col] = f2bf(v);
      }
    }
  }
}

// ---------- flash attention v3: 4-wave blocks, LDS-shared K/V, double-buffered ----------
template <bool CAUSAL>
__global__ __launch_bounds__(256, 4) void attn3(const u16* __restrict__ qb, long q_bstride, int q_rstride,
                                                const u16* __restrict__ kbp, long k_bstride, int k_rstride,
                                                const u16* __restrict__ vt,
                                                u16* __restrict__ yb, long y_bstride, int y_rstride,
                                                int Nk, int H) {
  __shared__ __align__(16) u16 Kl[2][2048];
  __shared__ __align__(16) u16 Vl[2][2048];
  const int tid = threadIdx.x;
  const int w = tid >> 6, l = tid & 63;
  const int qi = l & 31, hi = l >> 5;

  const int nwg = gridDim.x;
  const int chunk = nwg >> 3;
  const int nb = (blockIdx.x & 7) * chunk + (blockIdx.x >> 3);
  const int bh = nb >> 3;
  const int bx6 = nb & 7;
  const int bx = (bx6 & 1) ? (7 - (bx6 >> 1)) : (bx6 >> 1);
  const int b = bh / H, h = bh % H;
  const int qr0 = bx * 128 + w * 32;
  const u16* qp = qb + (long)b * q_bstride + h * 64;
  const u16* kp = kbp + (long)b * k_bstride + h * 64;
  const u16* vp = vt + (long)bh * 64 * Nk;
  const float CL = 0.125f * 1.44269504088896340736f;

  const u16* qrow = qp + (long)(qr0 + qi) * q_rstride + hi * 8;
  short8 qf0 = *(const short8*)(qrow);
  short8 qf1 = *(const short8*)(qrow + 16);
  short8 qf2 = *(const short8*)(qrow + 32);
  short8 qf3 = *(const short8*)(qrow + 48);

  f32x16 ot0, ot1;
#pragma unroll
  for (int i = 0; i < 16; i++) { ot0[i] = 0.f; ot1[i] = 0.f; }
  float m_run = -INFINITY, l_run = 0.f;

  const int krow_ = tid >> 3, kcb_ = (tid & 7) ^ (krow_ & 7);
  const int vrow_ = tid >> 2, vcb_ = (tid & 3) ^ (vrow_ & 3);
  const u16* kg = kp + (long)krow_ * k_rstride + kcb_ * 8;
  const u16* vg = vp + (long)vrow_ * Nk + vcb_ * 8;

  const int ntiles = CAUSAL ? (bx * 4 + 4) : (Nk >> 5);
  const int mytile = bx * 4 + w;

  gload_lds16(kg, &Kl[0][tid * 8]);
  gload_lds16(vg, &Vl[0][tid * 8]);
  __syncthreads();

  for (int t = 0; t < ntiles; ++t) {
    const int cur = t & 1;
    if (t + 1 < ntiles) {
      gload_lds16(kg + (t + 1) * 32 * (long)k_rstride, &Kl[cur ^ 1][tid * 8]);
      gload_lds16(vg + (t + 1) * 32, &Vl[cur ^ 1][tid * 8]);
    }
    if (!CAUSAL || t <= mytile) {
      const int kb0 = t * 32;
      const bool dmask = CAUSAL && (t == mytile);
      short8 kf[4];
#pragma unroll
      for (int ks = 0; ks < 4; ks++)
        kf[ks] = *(const short8*)&Kl[cur][(qi << 6) + (((2 * ks + hi) ^ (qi & 7)) << 3)];
      f32x16 sc;
#pragma unroll
      for (int i = 0; i < 16; i++) sc[i] = 0.f;
      sc = __builtin_amdgcn_mfma_f32_32x32x16_bf16(kf[0], qf0, sc, 0, 0, 0);
      sc = __builtin_amdgcn_mfma_f32_32x32x16_bf16(kf[1], qf1, sc, 0, 0, 0);
      sc = __builtin_amdgcn_mfma_f32_32x32x16_bf16(kf[2], qf2, sc, 0, 0, 0);
      sc = __builtin_amdgcn_mfma_f32_32x32x16_bf16(kf[3], qf3, sc, 0, 0, 0);
      if (dmask) {
#pragma unroll
        for (int r = 0; r < 16; r++) {
          int key = kb0 + (r & 3) + 8 * (r >> 2) + 4 * hi;
          if (key > qr0 + qi) sc[r] = -INFINITY;
        }
      }
      float mx = sc[0];
#pragma unroll
      for (int r = 1; r < 16; r++) mx = fmaxf(mx, sc[r]);
      { float a = mx, bb2 = mx; plswapf(a, bb2); mx = fmaxf(a, bb2); }
      float mnew = fmaxf(m_run, mx);
      float alpha = exp2f((m_run - mnew) * CL);
      m_run = mnew;
      float p[16];
      float ssum = 0.f;
#pragma unroll
      for (int r = 0; r < 16; r++) { p[r] = exp2f((sc[r] - mnew) * CL); ssum += p[r]; }
      { float a = ssum, bb2 = ssum; plswapf(a, bb2); ssum = a + bb2; }
      l_run = l_run * alpha + ssum;
#pragma unroll
      for (int i = 0; i < 16; i++) { ot0[i] *= alpha; ot1[i] *= alpha; }
      u32 w0 = cvtpk_bf16(p[0], p[1]);
      u32 w1 = cvtpk_bf16(p[2], p[3]);
      u32 w2 = cvtpk_bf16(p[4], p[5]);
      u32 w3 = cvtpk_bf16(p[6], p[7]);
      plswap32(w0, w2);
      plswap32(w1, w3);
      u32 w4 = cvtpk_bf16(p[8], p[9]);
      u32 w5 = cvtpk_bf16(p[10], p[11]);
      u32 w6 = cvtpk_bf16(p[12], p[13]);
      u32 w7 = cvtpk_bf16(p[14], p[15]);
      plswap32(w4, w6);
      plswap32(w5, w7);
      union { u32 u[4]; short8 s; } ua0, ua1;
      ua0.u[0] = w0; ua0.u[1] = w1; ua0.u[2] = w2; ua0.u[3] = w3;
      ua1.u[0] = w4; ua1.u[1] = w5; ua1.u[2] = w6; ua1.u[3] = w7;
      short8 va00 = *(const short8*)&Vl[cur][(qi << 5) + (((hi) ^ (qi & 3)) << 3)];
      short8 va01 = *(const short8*)&Vl[cur][(qi << 5) + (((2 + hi) ^ (qi & 3)) << 3)];
      short8 va10 = *(const short8*)&Vl[cur][((qi + 32) << 5) + (((hi) ^ (qi & 3)) << 3)];
      short8 va11 = *(const short8*)&Vl[cur][((qi + 32) << 5) + (((2 + hi) ^ (qi & 3)) << 3)];
      ot0 = __builtin_amdgcn_mfma_f32_32x32x16_bf16(va00, ua0.s, ot0, 0, 0, 0);
      ot0 = __builtin_amdgcn_mfma_f32_32x32x16_bf16(va01, ua1.s, ot0, 0, 0, 0);
      ot1 = __builtin_amdgcn_mfma_f32_32x32x16_bf16(va10, ua0.s, ot1, 0, 0, 0);
      ot1 = __builtin_amdgcn_mfma_f32_32x32x16_bf16(va11, ua1.s, ot1, 0, 0, 0);
    }
    __syncthreads();
  }

  float inv = 1.f / l_run;
  u16* yp = yb + (long)b * y_bstride + h * 64 + (long)(qr0 + qi) * y_rstride;
#pragma unroll
  for (int g = 0; g < 4; g++) {
    uint2 s0;
    s0.x = cvtpk_bf16(ot0[4 * g + 0] * inv, ot0[4 * g + 1] * inv);
    s0.y = cvtpk_bf16(ot0[4 * g + 2] * inv, ot0[4 * g + 3] * inv);
    *(uint2*)(yp + 8 * g + 4 * hi) = s0;
    uint2 s1;
    s1.x = cvtpk_bf16(ot1[4 * g + 0] * inv, ot1[4 * g + 1] * inv);
    s1.y = cvtpk_bf16(ot1[4 * g + 2] * inv, ot1[4 * g + 3] * inv);
    *(uint2*)(yp + 32 + 8 * g + 4 * hi) = s1;
  }
}

// ---------- layernorm (optionally + residual), f32 in, f32+bf16 out ----------
__global__ __launch_bounds__(256) void ln_k(const float* x, const float* res,
                                            const float* g, const float* bb,
                                            float* outF, u16* outB, int C) {
  __shared__ float red[8];
  long row = blockIdx.x;
  const float* xp = x + row * C;
  int i0 = threadIdx.x * 4;
  float4 v = *(const float4*)(xp + i0);
  if (res) {
    float4 r = *(const float4*)(res + row * C + i0);
    v.x += r.x; v.y += r.y; v.z += r.z; v.w += r.w;
  }
  float s = v.x + v.y + v.z + v.w;
  float sq = v.x * v.x + v.y * v.y + v.z * v.z + v.w * v.w;
#pragma unroll
  for (int off = 1; off < 64; off <<= 1) {
    s += __shfl_xor(s, off, 64);
    sq += __shfl_xor(sq, off, 64);
  }
  int w = threadIdx.x >> 6, l = threadIdx.x & 63;
  if (l == 0) { red[w] = s; red[4 + w] = sq; }
  __syncthreads();
  s = red[0] + red[1] + red[2] + red[3];
  sq = red[4] + red[5] + red[6] + red[7];
  float mean = s * (1.f / 1024.f);
  float var = sq * (1.f / 1024.f) - mean * mean;
  float rstd = rsqrtf(var + 1e-5f);
  float4 gv = *(const float4*)(g + i0);
  float4 bv = *(const float4*)(bb + i0);
  float o0 = (v.x - mean) * rstd * gv.x + bv.x;
  float o1 = (v.y - mean) * rstd * gv.y + bv.y;
  float o2 = (v.z - mean) * rstd * gv.z + bv.z;
  float o3 = (v.w - mean) * rstd * gv.w + bv.w;
  if (outF) {
    float4 ov; ov.x = o0; ov.y = o1; ov.z = o2; ov.w = o3;
    *(float4*)(outF + row * C + i0) = ov;
  }
  if (outB) {
    unsigned long long p = (unsigned long long)f2bf(o0) |
                           ((unsigned long long)f2bf(o1) << 16) |
                           ((unsigned long long)f2bf(o2) << 32) |
                           ((unsigned long long)f2bf(o3) << 48);
    *(unsigned long long*)(outB + row * C + i0) = p;
  }
}

// ---------- launcher ----------
extern "C" void kernel_launch(void* const* d_in, const int* in_sizes, int n_in,
                              void* d_out, int out_size, void* d_ws, size_t ws_size,
                              hipStream_t stream) {
  const int B = 8, N = 1024, T = 512, C = 1024, H = 16;
  const float* prev = (const float*)d_in[0];
  const float* enc = (const float*)d_in[1];
  const float* sa_w = (const float*)d_in[2];
  const float* sa_b = (const float*)d_in[3];
  const float* sa_pw = (const float*)d_in[4];
  const float* sa_pb = (const float*)d_in[5];
  const float* caq_w = (const float*)d_in[6];
  const float* caq_b = (const float*)d_in[7];
  const float* cakv_w = (const float*)d_in[8];
  const float* cakv_b = (const float*)d_in[9];
  const float* ca_pw = (const float*)d_in[10];
  const float* ca_pb = (const float*)d_in[11];
  const float* fc_w = (const float*)d_in[12];
  const float* fc_b = (const float*)d_in[13];
  const float* proj_w = (const float*)d_in[14];
  const float* proj_b = (const float*)d_in[15];
  const float* ln1_g = (const float*)d_in[16];
  const float* ln1_b = (const float*)d_in[17];
  const float* ln2_g = (const float*)d_in[18];
  const float* ln2_b = (const float*)d_in[19];
  const float* ln3_g = (const float*)d_in[20];
  const float* ln3_b = (const float*)d_in[21];

  char* ws = (char*)d_ws;
  u16* wT_sa   = (u16*)(ws + 0);               // [3072,1024]
  u16* wT_sapw = (u16*)(ws + 6291456);         // [1024,1024]
  u16* wT_caq  = (u16*)(ws + 8388608);         // [1024,1024]
  u16* wT_cakv = (u16*)(ws + 10485760);        // [2048,1024]
  u16* wT_capw = (u16*)(ws + 14680064);        // [1024,1024]
  u16* wT_fc   = (u16*)(ws + 16777216);        // [4096,1024]
  u16* wT_proj = (u16*)(ws + 25165824);        // [1024,4096]
  u16* abf   = (u16*)(ws + 33554432);
  u16* encbf = (u16*)(ws + 50331648);
  u16* qkv   = (u16*)(ws + 58720256);
  u16* vt1   = (u16*)(ws + 109051904);
  u16* ybf   = (u16*)(ws + 125829120);
  float* pf32 = (float*)(ws + 142606336);
  float* x1f  = (float*)(ws + 176160768);
  u16* x1bf  = (u16*)(ws + 209715200);
  u16* kvbf  = (u16*)(ws + 226492416);
  u16* y2bf  = abf;
  u16* vt2   = encbf;
  u16* q2bf  = ybf;
  u16* hbf   = qkv;

  cvt_f32_bf16<<<8192, 256, 0, stream>>>(prev, abf, (long)B * N * C);
  cvt_f32_bf16<<<4096, 256, 0, stream>>>(enc, encbf, (long)B * T * C);
  wtrans<<<dim3(96, 32), dim3(32, 8), 0, stream>>>(sa_w, wT_sa, 1024, 3072);
  wtrans<<<dim3(32, 32), dim3(32, 8), 0, stream>>>(sa_pw, wT_sapw, 1024, 1024);
  wtrans<<<dim3(32, 32), dim3(32, 8), 0, stream>>>(caq_w, wT_caq, 1024, 1024);
  wtrans<<<dim3(64, 32), dim3(32, 8), 0, stream>>>(cakv_w, wT_cakv, 1024, 2048);
  wtrans<<<dim3(32, 32), dim3(32, 8), 0, stream>>>(ca_pw, wT_capw, 1024, 1024);
  wtrans<<<dim3(128, 32), dim3(32, 8), 0, stream>>>(fc_w, wT_fc, 1024, 4096);
  wtrans<<<dim3(32, 128), dim3(32, 8), 0, stream>>>(proj_w, wT_proj, 4096, 1024);
  // qkv: M=8192 N=3072 K=1024
  gemm3<128, 0><<<768, 512, 0, stream>>>(abf, wT_sa, sa_b, nullptr, qkv, 8192, 3072, 1024);
  vtrans<<<dim3(16, 128), 256, 0, stream>>>(qkv, vt1, 1024, 3 * C, 2 * C, H);
  attn3<true><<<dim3(1024), 256, 0, stream>>>(qkv, (long)N * 3 * C, 3 * C,
                                              qkv + C, (long)N * 3 * C, 3 * C,
                                              vt1, ybf, (long)N * C, C, N, H);
  gemm3<128, 0><<<256, 512, 0, stream>>>(ybf, wT_sapw, sa_pb, pf32, nullptr, 8192, 1024, 1024);
  ln_k<<<8192, 256, 0, stream>>>(pf32, nullptr, ln1_g, ln1_b, x1f, x1bf, C);
  gemm3<128, 0><<<256, 512, 0, stream>>>(x1bf, wT_caq, caq_b, nullptr, q2bf, 8192, 1024, 1024);
  gemm3<128, 0><<<256, 512, 0, stream>>>(encbf, wT_cakv, cakv_b, nullptr, kvbf, 4096, 2048, 1024);
  vtrans<<<dim3(8, 128), 256, 0, stream>>>(kvbf, vt2, 512, 2 * C, C, H);
  attn3<false><<<dim3(1024), 256, 0, stream>>>(q2bf, (long)N * C, C,
                                               kvbf, (long)T * 2 * C, 2 * C,
                                               vt2, y2bf, (long)N * C, C, T, H);
  gemm3<128, 0><<<256, 512, 0, stream>>>(y2bf, wT_capw, ca_pb, pf32, nullptr, 8192, 1024, 1024);
  ln_k<<<8192, 256, 0, stream>>>(pf32, x1f, ln2_g, ln2_b, x1f, x1bf, C);
  // fc: M=8192 N=4096 K=1024, GELU
  gemm3<256, 1><<<512, 512, 0, stream>>>(x1bf, wT_fc, fc_b, nullptr, hbf, 8192, 4096, 1024);
  // proj: M=8192 N=1024 K=4096
  gemm3<128, 0><<<256, 512, 0, stream>>>(hbf, wT_proj, proj_b, pf32, nullptr, 8192, 1024, 4096);
  ln_k<<<8192, 256, 0, stream>>>(pf32, x1f, ln3_g, ln3_b, (float*)d_out, nullptr, C);
}

// Round 6
// 584.817 us; speedup vs baseline: 1.5057x; 1.0190x over previous
//
#include <hip/hip_runtime.h>

typedef unsigned short u16;
typedef unsigned int u32;
typedef __attribute__((ext_vector_type(8))) short short8;
typedef __attribute__((ext_vector_type(4))) float f32x4;
typedef __attribute__((ext_vector_type(16))) float f32x16;

// ---------- helpers ----------
__device__ __forceinline__ u16 f2bf(float f) {
  union { float f; unsigned int u; } v; v.f = f;
  unsigned int r = v.u + 0x7FFFu + ((v.u >> 16) & 1u);  // RNE
  return (u16)(r >> 16);
}

__device__ __forceinline__ void gload_lds16(const void* g, void* l) {
  __builtin_amdgcn_global_load_lds((const __attribute__((address_space(1))) void*)g,
                                   (__attribute__((address_space(3))) void*)l, 16, 0, 0);
}

__device__ __forceinline__ u32 cvtpk_bf16(float lo, float hi) {
  u32 r;
  asm("v_cvt_pk_bf16_f32 %0, %1, %2" : "=v"(r) : "v"(lo), "v"(hi));
  return r;
}

__device__ __forceinline__ void plswap32(u32& a, u32& b) {
#if __has_builtin(__builtin_amdgcn_permlane32_swap)
  auto r = __builtin_amdgcn_permlane32_swap((int)a, (int)b, false, false);
  a = (u32)r[0]; b = (u32)r[1];
#else
  asm volatile("v_permlane32_swap_b32 %0, %1" : "+v"(a), "+v"(b));
#endif
}

__device__ __forceinline__ void plswapf(float& a, float& b) {
  union { float f; u32 u; } x, y; x.f = a; y.f = b;
  plswap32(x.u, y.u);
  a = x.f; b = y.f;
}

template <int N>
__device__ __forceinline__ void wait_vm() {
  if constexpr (N == 0) asm volatile("s_waitcnt vmcnt(0)" ::: "memory");
  else if constexpr (N == 3) asm volatile("s_waitcnt vmcnt(3)" ::: "memory");
  else if constexpr (N == 4) asm volatile("s_waitcnt vmcnt(4)" ::: "memory");
  else if constexpr (N == 6) asm volatile("s_waitcnt vmcnt(6)" ::: "memory");
  else if constexpr (N == 8) asm volatile("s_waitcnt vmcnt(8)" ::: "memory");
}
__device__ __forceinline__ void wait_lgkm0() {
  asm volatile("s_waitcnt lgkmcnt(0)" ::: "memory");
}
#define SBAR() __builtin_amdgcn_sched_barrier(0)

// ---------- f32 -> bf16 convert ----------
__global__ __launch_bounds__(256) void cvt_f32_bf16(const float* __restrict__ in,
                                                    u16* __restrict__ out, long n) {
  long i = ((long)blockIdx.x * 256 + threadIdx.x) * 4;
  if (i + 3 < n) {
    float4 v = *(const float4*)(in + i);
    unsigned long long p = (unsigned long long)f2bf(v.x) |
                           ((unsigned long long)f2bf(v.y) << 16) |
                           ((unsigned long long)f2bf(v.z) << 32) |
                           ((unsigned long long)f2bf(v.w) << 48);
    *(unsigned long long*)(out + i) = p;
  }
}

// ---------- weight transpose+convert: W[K,N] f32 -> WT[N,K] bf16 ----------
__global__ __launch_bounds__(256) void wtrans(const float* __restrict__ W,
                                              u16* __restrict__ WT, int K, int N) {
  __shared__ float t[32][33];
  int n0 = blockIdx.x * 32, k0 = blockIdx.y * 32;
  int tx = threadIdx.x, ty = threadIdx.y;
#pragma unroll
  for (int r = 0; r < 4; r++)
    t[ty + r * 8][tx] = W[(long)(k0 + ty + r * 8) * N + n0 + tx];
  __syncthreads();
#pragma unroll
  for (int r = 0; r < 4; r++)
    WT[(long)(n0 + ty + r * 8) * K + k0 + tx] = f2bf(t[tx][ty + r * 8]);
}

// ---------- V transpose: [b, n, head_off + h*64 + d] -> [bh][d][n] ----------
__global__ __launch_bounds__(256) void vtrans(const u16* __restrict__ src,
                                              u16* __restrict__ dst,
                                              int rows, int rstride, int head_off, int H) {
  __shared__ u16 t[64][65];
  int bh = blockIdx.y;
  int b = bh / H, h = bh % H;
  long n0 = (long)blockIdx.x * 64;
  const u16* s = src + (long)b * rows * rstride + head_off + h * 64;
  int q = threadIdx.x >> 6, ln = threadIdx.x & 63;
#pragma unroll
  for (int r = 0; r < 16; r++) {
    int nl = q * 16 + r;
    t[nl][ln] = s[(n0 + nl) * (long)rstride + ln];
  }
  __syncthreads();
  u16* d = dst + (long)bh * 64 * rows;
#pragma unroll
  for (int r = 0; r < 16; r++) {
    int dd = q * 16 + r;
    d[(long)dd * rows + n0 + ln] = t[ln][dd];
  }
}

// ---------- gemm3: 4-phase/K-tile, m201-order phases ----------
// BM=256, BK=64 (2 K-halves), 8 waves (2m x 4n), per-wave out 128 x BN/4.
// Phase = { ds_read regs for THIS phase's MFMA; issue 1 half-stage;
//           s_barrier (reads stay in flight); lgkmcnt(0); setprio(1);
//           16 MFMA; setprio(0); [counted vmcnt on odd phases]; s_barrier }.
// vmcnt ledger (A-half=2 loads, B-half=BLB): steady 4+2*BLB at ph1/ph3;
// tail 2+BLB then 0. Stage distance 5-6 phases; buffer reuse always
// separated from last read by >=1 barrier (audited).
template <int BN, int GELU>
__global__ __launch_bounds__(512, 1) void gemm3(const u16* __restrict__ A,
                                                const u16* __restrict__ BT,
                                                const float* __restrict__ bias,
                                                float* __restrict__ outF,
                                                u16* __restrict__ outB,
                                                int M, int N, int K) {
  constexpr int BM = 256;
  constexpr int NR = BN / 64;       // n frags per wave
  constexpr int BLB = BN / 128;     // B gload_lds per thread per half-unit
  constexpr int VMS = 4 + 2 * BLB;  // steady vmcnt
  constexpr int VML = 2 + BLB;      // tail
  __shared__ __align__(16) u16 Al[2][2][BM * 32];
  __shared__ __align__(16) u16 Bl[2][2][BN * 32];
  const int tid = threadIdx.x;
  const int w = tid >> 6, l = tid & 63;
  const int wr = w >> 2, wc = w & 3;
  const int lr = l & 15, lg = l >> 4;

  // XCD mapping: each XCD owns nx/8 contiguous bx (A slabs), streams by
  const int nx = M >> 8;
  const int gpx = nx >> 3;
  const int hgt = blockIdx.x;
  const int xcd = hgt & 7, j = hgt >> 3;
  const int bx = xcd * gpx + (j % gpx);
  const int by = j / gpx;
  const long m0 = (long)bx * BM, n0 = (long)by * BN;

  const int nt = K >> 6;

  // stage source bases (inverse-swizzled global, linear LDS dest)
  const u16* baseA[2];
#pragma unroll
  for (int rr = 0; rr < 2; rr++) {
    int e = rr * 512 + tid, row = e >> 2;
    int kk = ((e & 3) - (row >> 1)) & 3;
    baseA[rr] = A + (m0 + row) * (long)K + kk * 8;
  }
  const u16* baseB[BLB];
#pragma unroll
  for (int rr = 0; rr < BLB; rr++) {
    int e = rr * 512 + tid, row = e >> 2;
    int kk = ((e & 3) - (row >> 1)) & 3;
    baseB[rr] = BT + (n0 + row) * (long)K + kk * 8;
  }

  auto stA = [&](int buf, int kh, int t) {
    if (t < nt) {
#pragma unroll
      for (int rr = 0; rr < 2; rr++)
        gload_lds16(baseA[rr] + (long)t * 64 + kh * 32, &Al[buf][kh][(rr * 512 + tid) * 8]);
    }
  };
  auto stB = [&](int buf, int kh, int t) {
    if (t < nt) {
#pragma unroll
      for (int rr = 0; rr < BLB; rr++)
        gload_lds16(baseB[rr] + (long)t * 64 + kh * 32, &Bl[buf][kh][(rr * 512 + tid) * 8]);
    }
  };

  f32x4 acc[8][NR];
#pragma unroll
  for (int i = 0; i < 8; i++)
#pragma unroll
    for (int nn = 0; nn < NR; nn++) acc[i][nn] = (f32x4){0.f, 0.f, 0.f, 0.f};

  // prologue: tile0 (both halves) + tile1 kh0, then wait tile0-kh0 landed
  stA(0, 0, 0); stB(0, 0, 0); stA(0, 1, 0); stB(0, 1, 0); stA(1, 0, 1); stB(1, 0, 1);
  wait_vm<VMS>();
  SBAR(); __builtin_amdgcn_s_barrier(); SBAR();

  for (int t = 0; t < nt; ++t) {
    const int bt = t & 1, nb = bt ^ 1;
#pragma unroll
    for (int kh = 0; kh < 2; kh++) {
      const u16* Ah = &Al[bt][kh][0];
      const u16* Bh = &Bl[bt][kh][0];
      short8 bf[NR], af[4];

      // ===== even phase (mm 0-3) =====
#pragma unroll
      for (int nn = 0; nn < NR; nn++) {
        int row = wc * (BN / 4) + nn * 16 + lr;
        bf[nn] = *(const short8*)&Bh[row * 32 + (((lg + (row >> 1)) & 3) << 3)];
      }
#pragma unroll
      for (int mm = 0; mm < 4; mm++) {
        int row = wr * 128 + mm * 16 + lr;
        af[mm] = *(const short8*)&Ah[row * 32 + (((lg + (row >> 1)) & 3) << 3)];
      }
      if (kh == 0) stA(nb, 1, t + 1); else stA(bt, 0, t + 2);
      SBAR(); __builtin_amdgcn_s_barrier(); SBAR();
      wait_lgkm0(); SBAR();
      __builtin_amdgcn_s_setprio(1);
#pragma unroll
      for (int mm = 0; mm < 4; mm++)
#pragma unroll
        for (int nn = 0; nn < NR; nn++)
          acc[mm][nn] = __builtin_amdgcn_mfma_f32_16x16x32_bf16(af[mm], bf[nn], acc[mm][nn], 0, 0, 0);
      __builtin_amdgcn_s_setprio(0);
      SBAR(); __builtin_amdgcn_s_barrier(); SBAR();

      // ===== odd phase (mm 4-7) =====
#pragma unroll
      for (int mm = 0; mm < 4; mm++) {
        int row = wr * 128 + (mm + 4) * 16 + lr;
        af[mm] = *(const short8*)&Ah[row * 32 + (((lg + (row >> 1)) & 3) << 3)];
      }
      if (kh == 0) stB(nb, 1, t + 1); else stB(bt, 0, t + 2);
      SBAR(); __builtin_amdgcn_s_barrier(); SBAR();
      wait_lgkm0(); SBAR();
      __builtin_amdgcn_s_setprio(1);
#pragma unroll
      for (int mm = 0; mm < 4; mm++)
#pragma unroll
        for (int nn = 0; nn < NR; nn++)
          acc[mm + 4][nn] = __builtin_amdgcn_mfma_f32_16x16x32_bf16(af[mm], bf[nn], acc[mm + 4][nn], 0, 0, 0);
      __builtin_amdgcn_s_setprio(0);
      // counted vmcnt AFTER the MFMA cluster (loads land under compute)
      if (kh == 0) {
        if (t + 1 < nt) wait_vm<VMS>(); else wait_vm<0>();
      } else {
        if (t + 2 < nt) wait_vm<VMS>();
        else if (t + 1 < nt) wait_vm<VML>();
      }
      SBAR(); __builtin_amdgcn_s_barrier(); SBAR();
    }
  }

  // epilogue: nn innermost so adjacent 32B col-segments merge into 64B writes
  float bv[NR];
#pragma unroll
  for (int nn = 0; nn < NR; nn++)
    bv[nn] = bias ? bias[n0 + wc * (BN / 4) + nn * 16 + lr] : 0.f;
#pragma unroll
  for (int mm = 0; mm < 8; mm++) {
#pragma unroll
    for (int i = 0; i < 4; i++) {
      const long row = m0 + wr * 128 + mm * 16 + lg * 4 + i;
#pragma unroll
      for (int nn = 0; nn < NR; nn++) {
        const long col = n0 + wc * (BN / 4) + nn * 16 + lr;
        float v = acc[mm][nn][i] + bv[nn];
        if (GELU) v = 0.5f * v * (1.f + erff(v * 0.70710678118654752f));
        if (outF) outF[row * N + col] = v;
        if (outB) outB[row * N + col] = f2bf(v);
      }
    }
  }
}

// ---------- flash attention v3: 4-wave blocks, LDS-shared K/V, double-buffered ----------
template <bool CAUSAL>
__global__ __launch_bounds__(256, 4) void attn3(const u16* __restrict__ qb, long q_bstride, int q_rstride,
                                                const u16* __restrict__ kbp, long k_bstride, int k_rstride,
                                                const u16* __restrict__ vt,
                                                u16* __restrict__ yb, long y_bstride, int y_rstride,
                                                int Nk, int H) {
  __shared__ __align__(16) u16 Kl[2][2048];
  __shared__ __align__(16) u16 Vl[2][2048];
  const int tid = threadIdx.x;
  const int w = tid >> 6, l = tid & 63;
  const int qi = l & 31, hi = l >> 5;

  const int nwg = gridDim.x;
  const int chunk = nwg >> 3;
  const int nb = (blockIdx.x & 7) * chunk + (blockIdx.x >> 3);
  const int bh = nb >> 3;
  const int bx6 = nb & 7;
  const int bx = (bx6 & 1) ? (7 - (bx6 >> 1)) : (bx6 >> 1);
  const int b = bh / H, h = bh % H;
  const int qr0 = bx * 128 + w * 32;
  const u16* qp = qb + (long)b * q_bstride + h * 64;
  const u16* kp = kbp + (long)b * k_bstride + h * 64;
  const u16* vp = vt + (long)bh * 64 * Nk;
  const float CL = 0.125f * 1.44269504088896340736f;

  const u16* qrow = qp + (long)(qr0 + qi) * q_rstride + hi * 8;
  short8 qf0 = *(const short8*)(qrow);
  short8 qf1 = *(const short8*)(qrow + 16);
  short8 qf2 = *(const short8*)(qrow + 32);
  short8 qf3 = *(const short8*)(qrow + 48);

  f32x16 ot0, ot1;
#pragma unroll
  for (int i = 0; i < 16; i++) { ot0[i] = 0.f; ot1[i] = 0.f; }
  float m_run = -INFINITY, l_run = 0.f;

  const int krow_ = tid >> 3, kcb_ = (tid & 7) ^ (krow_ & 7);
  const int vrow_ = tid >> 2, vcb_ = (tid & 3) ^ (vrow_ & 3);
  const u16* kg = kp + (long)krow_ * k_rstride + kcb_ * 8;
  const u16* vg = vp + (long)vrow_ * Nk + vcb_ * 8;

  const int ntiles = CAUSAL ? (bx * 4 + 4) : (Nk >> 5);
  const int mytile = bx * 4 + w;

  gload_lds16(kg, &Kl[0][tid * 8]);
  gload_lds16(vg, &Vl[0][tid * 8]);
  __syncthreads();

  for (int t = 0; t < ntiles; ++t) {
    const int cur = t & 1;
    if (t + 1 < ntiles) {
      gload_lds16(kg + (t + 1) * 32 * (long)k_rstride, &Kl[cur ^ 1][tid * 8]);
      gload_lds16(vg + (t + 1) * 32, &Vl[cur ^ 1][tid * 8]);
    }
    if (!CAUSAL || t <= mytile) {
      const int kb0 = t * 32;
      const bool dmask = CAUSAL && (t == mytile);
      short8 kf[4];
#pragma unroll
      for (int ks = 0; ks < 4; ks++)
        kf[ks] = *(const short8*)&Kl[cur][(qi << 6) + (((2 * ks + hi) ^ (qi & 7)) << 3)];
      f32x16 sc;
#pragma unroll
      for (int i = 0; i < 16; i++) sc[i] = 0.f;
      sc = __builtin_amdgcn_mfma_f32_32x32x16_bf16(kf[0], qf0, sc, 0, 0, 0);
      sc = __builtin_amdgcn_mfma_f32_32x32x16_bf16(kf[1], qf1, sc, 0, 0, 0);
      sc = __builtin_amdgcn_mfma_f32_32x32x16_bf16(kf[2], qf2, sc, 0, 0, 0);
      sc = __builtin_amdgcn_mfma_f32_32x32x16_bf16(kf[3], qf3, sc, 0, 0, 0);
      if (dmask) {
#pragma unroll
        for (int r = 0; r < 16; r++) {
          int key = kb0 + (r & 3) + 8 * (r >> 2) + 4 * hi;
          if (key > qr0 + qi) sc[r] = -INFINITY;
        }
      }
      float mx = sc[0];
#pragma unroll
      for (int r = 1; r < 16; r++) mx = fmaxf(mx, sc[r]);
      { float a = mx, bb2 = mx; plswapf(a, bb2); mx = fmaxf(a, bb2); }
      float mnew = fmaxf(m_run, mx);
      float alpha = exp2f((m_run - mnew) * CL);
      m_run = mnew;
      float p[16];
      float ssum = 0.f;
#pragma unroll
      for (int r = 0; r < 16; r++) { p[r] = exp2f((sc[r] - mnew) * CL); ssum += p[r]; }
      { float a = ssum, bb2 = ssum; plswapf(a, bb2); ssum = a + bb2; }
      l_run = l_run * alpha + ssum;
#pragma unroll
      for (int i = 0; i < 16; i++) { ot0[i] *= alpha; ot1[i] *= alpha; }
      u32 w0 = cvtpk_bf16(p[0], p[1]);
      u32 w1 = cvtpk_bf16(p[2], p[3]);
      u32 w2 = cvtpk_bf16(p[4], p[5]);
      u32 w3 = cvtpk_bf16(p[6], p[7]);
      plswap32(w0, w2);
      plswap32(w1, w3);
      u32 w4 = cvtpk_bf16(p[8], p[9]);
      u32 w5 = cvtpk_bf16(p[10], p[11]);
      u32 w6 = cvtpk_bf16(p[12], p[13]);
      u32 w7 = cvtpk_bf16(p[14], p[15]);
      plswap32(w4, w6);
      plswap32(w5, w7);
      union { u32 u[4]; short8 s; } ua0, ua1;
      ua0.u[0] = w0; ua0.u[1] = w1; ua0.u[2] = w2; ua0.u[3] = w3;
      ua1.u[0] = w4; ua1.u[1] = w5; ua1.u[2] = w6; ua1.u[3] = w7;
      short8 va00 = *(const short8*)&Vl[cur][(qi << 5) + (((hi) ^ (qi & 3)) << 3)];
      short8 va01 = *(const short8*)&Vl[cur][(qi << 5) + (((2 + hi) ^ (qi & 3)) << 3)];
      short8 va10 = *(const short8*)&Vl[cur][((qi + 32) << 5) + (((hi) ^ (qi & 3)) << 3)];
      short8 va11 = *(const short8*)&Vl[cur][((qi + 32) << 5) + (((2 + hi) ^ (qi & 3)) << 3)];
      ot0 = __builtin_amdgcn_mfma_f32_32x32x16_bf16(va00, ua0.s, ot0, 0, 0, 0);
      ot0 = __builtin_amdgcn_mfma_f32_32x32x16_bf16(va01, ua1.s, ot0, 0, 0, 0);
      ot1 = __builtin_amdgcn_mfma_f32_32x32x16_bf16(va10, ua0.s, ot1, 0, 0, 0);
      ot1 = __builtin_amdgcn_mfma_f32_32x32x16_bf16(va11, ua1.s, ot1, 0, 0, 0);
    }
    __syncthreads();
  }

  float inv = 1.f / l_run;
  u16* yp = yb + (long)b * y_bstride + h * 64 + (long)(qr0 + qi) * y_rstride;
#pragma unroll
  for (int g = 0; g < 4; g++) {
    uint2 s0;
    s0.x = cvtpk_bf16(ot0[4 * g + 0] * inv, ot0[4 * g + 1] * inv);
    s0.y = cvtpk_bf16(ot0[4 * g + 2] * inv, ot0[4 * g + 3] * inv);
    *(uint2*)(yp + 8 * g + 4 * hi) = s0;
    uint2 s1;
    s1.x = cvtpk_bf16(ot1[4 * g + 0] * inv, ot1[4 * g + 1] * inv);
    s1.y = cvtpk_bf16(ot1[4 * g + 2] * inv, ot1[4 * g + 3] * inv);
    *(uint2*)(yp + 32 + 8 * g + 4 * hi) = s1;
  }
}

// ---------- layernorm (optionally + residual), f32 in, f32+bf16 out ----------
__global__ __launch_bounds__(256) void ln_k(const float* x, const float* res,
                                            const float* g, const float* bb,
                                            float* outF, u16* outB, int C) {
  __shared__ float red[8];
  long row = blockIdx.x;
  const float* xp = x + row * C;
  int i0 = threadIdx.x * 4;
  float4 v = *(const float4*)(xp + i0);
  if (res) {
    float4 r = *(const float4*)(res + row * C + i0);
    v.x += r.x; v.y += r.y; v.z += r.z; v.w += r.w;
  }
  float s = v.x + v.y + v.z + v.w;
  float sq = v.x * v.x + v.y * v.y + v.z * v.z + v.w * v.w;
#pragma unroll
  for (int off = 1; off < 64; off <<= 1) {
    s += __shfl_xor(s, off, 64);
    sq += __shfl_xor(sq, off, 64);
  }
  int w = threadIdx.x >> 6, l = threadIdx.x & 63;
  if (l == 0) { red[w] = s; red[4 + w] = sq; }
  __syncthreads();
  s = red[0] + red[1] + red[2] + red[3];
  sq = red[4] + red[5] + red[6] + red[7];
  float mean = s * (1.f / 1024.f);
  float var = sq * (1.f / 1024.f) - mean * mean;
  float rstd = rsqrtf(var + 1e-5f);
  float4 gv = *(const float4*)(g + i0);
  float4 bv = *(const float4*)(bb + i0);
  float o0 = (v.x - mean) * rstd * gv.x + bv.x;
  float o1 = (v.y - mean) * rstd * gv.y + bv.y;
  float o2 = (v.z - mean) * rstd * gv.z + bv.z;
  float o3 = (v.w - mean) * rstd * gv.w + bv.w;
  if (outF) {
    float4 ov; ov.x = o0; ov.y = o1; ov.z = o2; ov.w = o3;
    *(float4*)(outF + row * C + i0) = ov;
  }
  if (outB) {
    unsigned long long p = (unsigned long long)f2bf(o0) |
                           ((unsigned long long)f2bf(o1) << 16) |
                           ((unsigned long long)f2bf(o2) << 32) |
                           ((unsigned long long)f2bf(o3) << 48);
    *(unsigned long long*)(outB + row * C + i0) = p;
  }
}

// ---------- launcher ----------
extern "C" void kernel_launch(void* const* d_in, const int* in_sizes, int n_in,
                              void* d_out, int out_size, void* d_ws, size_t ws_size,
                              hipStream_t stream) {
  const int B = 8, N = 1024, T = 512, C = 1024, H = 16;
  const float* prev = (const float*)d_in[0];
  const float* enc = (const float*)d_in[1];
  const float* sa_w = (const float*)d_in[2];
  const float* sa_b = (const float*)d_in[3];
  const float* sa_pw = (const float*)d_in[4];
  const float* sa_pb = (const float*)d_in[5];
  const float* caq_w = (const float*)d_in[6];
  const float* caq_b = (const float*)d_in[7];
  const float* cakv_w = (const float*)d_in[8];
  const float* cakv_b = (const float*)d_in[9];
  const float* ca_pw = (const float*)d_in[10];
  const float* ca_pb = (const float*)d_in[11];
  const float* fc_w = (const float*)d_in[12];
  const float* fc_b = (const float*)d_in[13];
  const float* proj_w = (const float*)d_in[14];
  const float* proj_b = (const float*)d_in[15];
  const float* ln1_g = (const float*)d_in[16];
  const float* ln1_b = (const float*)d_in[17];
  const float* ln2_g = (const float*)d_in[18];
  const float* ln2_b = (const float*)d_in[19];
  const float* ln3_g = (const float*)d_in[20];
  const float* ln3_b = (const float*)d_in[21];

  char* ws = (char*)d_ws;
  u16* wT_sa   = (u16*)(ws + 0);               // [3072,1024]
  u16* wT_sapw = (u16*)(ws + 6291456);         // [1024,1024]
  u16* wT_caq  = (u16*)(ws + 8388608);         // [1024,1024]
  u16* wT_cakv = (u16*)(ws + 10485760);        // [2048,1024]
  u16* wT_capw = (u16*)(ws + 14680064);        // [1024,1024]
  u16* wT_fc   = (u16*)(ws + 16777216);        // [4096,1024]
  u16* wT_proj = (u16*)(ws + 25165824);        // [1024,4096]
  u16* abf   = (u16*)(ws + 33554432);
  u16* encbf = (u16*)(ws + 50331648);
  u16* qkv   = (u16*)(ws + 58720256);
  u16* vt1   = (u16*)(ws + 109051904);
  u16* ybf   = (u16*)(ws + 125829120);
  float* pf32 = (float*)(ws + 142606336);
  float* x1f  = (float*)(ws + 176160768);
  u16* x1bf  = (u16*)(ws + 209715200);
  u16* kvbf  = (u16*)(ws + 226492416);
  u16* y2bf  = abf;
  u16* vt2   = encbf;
  u16* q2bf  = ybf;
  u16* hbf   = qkv;

  cvt_f32_bf16<<<8192, 256, 0, stream>>>(prev, abf, (long)B * N * C);
  cvt_f32_bf16<<<4096, 256, 0, stream>>>(enc, encbf, (long)B * T * C);
  wtrans<<<dim3(96, 32), dim3(32, 8), 0, stream>>>(sa_w, wT_sa, 1024, 3072);
  wtrans<<<dim3(32, 32), dim3(32, 8), 0, stream>>>(sa_pw, wT_sapw, 1024, 1024);
  wtrans<<<dim3(32, 32), dim3(32, 8), 0, stream>>>(caq_w, wT_caq, 1024, 1024);
  wtrans<<<dim3(64, 32), dim3(32, 8), 0, stream>>>(cakv_w, wT_cakv, 1024, 2048);
  wtrans<<<dim3(32, 32), dim3(32, 8), 0, stream>>>(ca_pw, wT_capw, 1024, 1024);
  wtrans<<<dim3(128, 32), dim3(32, 8), 0, stream>>>(fc_w, wT_fc, 1024, 4096);
  wtrans<<<dim3(32, 128), dim3(32, 8), 0, stream>>>(proj_w, wT_proj, 4096, 1024);
  // qkv: M=8192 N=3072 K=1024
  gemm3<128, 0><<<768, 512, 0, stream>>>(abf, wT_sa, sa_b, nullptr, qkv, 8192, 3072, 1024);
  vtrans<<<dim3(16, 128), 256, 0, stream>>>(qkv, vt1, 1024, 3 * C, 2 * C, H);
  attn3<true><<<dim3(1024), 256, 0, stream>>>(qkv, (long)N * 3 * C, 3 * C,
                                              qkv + C, (long)N * 3 * C, 3 * C,
                                              vt1, ybf, (long)N * C, C, N, H);
  gemm3<128, 0><<<256, 512, 0, stream>>>(ybf, wT_sapw, sa_pb, pf32, nullptr, 8192, 1024, 1024);
  ln_k<<<8192, 256, 0, stream>>>(pf32, nullptr, ln1_g, ln1_b, x1f, x1bf, C);
  gemm3<128, 0><<<256, 512, 0, stream>>>(x1bf, wT_caq, caq_b, nullptr, q2bf, 8192, 1024, 1024);
  gemm3<128, 0><<<256, 512, 0, stream>>>(encbf, wT_cakv, cakv_b, nullptr, kvbf, 4096, 2048, 1024);
  vtrans<<<dim3(8, 128), 256, 0, stream>>>(kvbf, vt2, 512, 2 * C, C, H);
  attn3<false><<<dim3(1024), 256, 0, stream>>>(q2bf, (long)N * C, C,
                                               kvbf, (long)T * 2 * C, 2 * C,
                                               vt2, y2bf, (long)N * C, C, T, H);
  gemm3<128, 0><<<256, 512, 0, stream>>>(y2bf, wT_capw, ca_pb, pf32, nullptr, 8192, 1024, 1024);
  ln_k<<<8192, 256, 0, stream>>>(pf32, x1f, ln2_g, ln2_b, x1f, x1bf, C);
  // fc: M=8192 N=4096 K=1024, GELU
  gemm3<256, 1><<<512, 512, 0, stream>>>(x1bf, wT_fc, fc_b, nullptr, hbf, 8192, 4096, 1024);
  // proj: M=8192 N=1024 K=4096
  gemm3<128, 0><<<256, 512, 0, stream>>>(hbf, wT_proj, proj_b, pf32, nullptr, 8192, 1024, 4096);
  ln_k<<<8192, 256, 0, stream>>>(pf32, x1f, ln3_g, ln3_b, (float*)d_out, nullptr, C);
}

// Round 7
// 531.337 us; speedup vs baseline: 1.6573x; 1.1007x over previous
//
#include <hip/hip_runtime.h>

typedef unsigned short u16;
typedef unsigned int u32;
typedef __attribute__((ext_vector_type(8))) short short8;
typedef __attribute__((ext_vector_type(4))) float f32x4;
typedef __attribute__((ext_vector_type(16))) float f32x16;

// ---------- helpers ----------
__device__ __forceinline__ u16 f2bf(float f) {
  union { float f; unsigned int u; } v; v.f = f;
  unsigned int r = v.u + 0x7FFFu + ((v.u >> 16) & 1u);  // RNE
  return (u16)(r >> 16);
}

__device__ __forceinline__ void gload_lds16(const void* g, void* l) {
  __builtin_amdgcn_global_load_lds((const __attribute__((address_space(1))) void*)g,
                                   (__attribute__((address_space(3))) void*)l, 16, 0, 0);
}

__device__ __forceinline__ u32 cvtpk_bf16(float lo, float hi) {
  u32 r;
  asm("v_cvt_pk_bf16_f32 %0, %1, %2" : "=v"(r) : "v"(lo), "v"(hi));
  return r;
}

__device__ __forceinline__ void plswap32(u32& a, u32& b) {
#if __has_builtin(__builtin_amdgcn_permlane32_swap)
  auto r = __builtin_amdgcn_permlane32_swap((int)a, (int)b, false, false);
  a = (u32)r[0]; b = (u32)r[1];
#else
  asm volatile("v_permlane32_swap_b32 %0, %1" : "+v"(a), "+v"(b));
#endif
}

__device__ __forceinline__ void plswapf(float& a, float& b) {
  union { float f; u32 u; } x, y; x.f = a; y.f = b;
  plswap32(x.u, y.u);
  a = x.f; b = y.f;
}

template <int N>
__device__ __forceinline__ void wait_vm() {
  if constexpr (N == 0) asm volatile("s_waitcnt vmcnt(0)" ::: "memory");
  else if constexpr (N == 3) asm volatile("s_waitcnt vmcnt(3)" ::: "memory");
  else if constexpr (N == 4) asm volatile("s_waitcnt vmcnt(4)" ::: "memory");
  else if constexpr (N == 6) asm volatile("s_waitcnt vmcnt(6)" ::: "memory");
  else if constexpr (N == 8) asm volatile("s_waitcnt vmcnt(8)" ::: "memory");
}
__device__ __forceinline__ void wait_lgkm0() {
  asm volatile("s_waitcnt lgkmcnt(0)" ::: "memory");
}
// counted lgkm gate; n is compile-time constant after unrolling
__device__ __forceinline__ void lgkm_gate(int n) {
  switch (n) {
    case 0: asm volatile("s_waitcnt lgkmcnt(0)" ::: "memory"); break;
    case 1: asm volatile("s_waitcnt lgkmcnt(1)" ::: "memory"); break;
    case 2: asm volatile("s_waitcnt lgkmcnt(2)" ::: "memory"); break;
    case 3: asm volatile("s_waitcnt lgkmcnt(3)" ::: "memory"); break;
    case 4: asm volatile("s_waitcnt lgkmcnt(4)" ::: "memory"); break;
    case 5: asm volatile("s_waitcnt lgkmcnt(5)" ::: "memory"); break;
    case 6: asm volatile("s_waitcnt lgkmcnt(6)" ::: "memory"); break;
    default: asm volatile("s_waitcnt lgkmcnt(7)" ::: "memory"); break;
  }
}
#define SBAR() __builtin_amdgcn_sched_barrier(0)

// order-pinned LDS read (asm volatile => issue order preserved for counted gates)
__device__ __forceinline__ u32 lds_off(const void* p) {
  return (u32)(size_t)(const __attribute__((address_space(3))) void*)p;
}
__device__ __forceinline__ short8 ds_read128(u32 off) {
  short8 d;
  asm volatile("ds_read_b128 %0, %1" : "=v"(d) : "v"(off));
  return d;
}

// ---------- f32 -> bf16 convert ----------
__global__ __launch_bounds__(256) void cvt_f32_bf16(const float* __restrict__ in,
                                                    u16* __restrict__ out, long n) {
  long i = ((long)blockIdx.x * 256 + threadIdx.x) * 4;
  if (i + 3 < n) {
    float4 v = *(const float4*)(in + i);
    unsigned long long p = (unsigned long long)f2bf(v.x) |
                           ((unsigned long long)f2bf(v.y) << 16) |
                           ((unsigned long long)f2bf(v.z) << 32) |
                           ((unsigned long long)f2bf(v.w) << 48);
    *(unsigned long long*)(out + i) = p;
  }
}

// ---------- weight transpose+convert: W[K,N] f32 -> WT[N,K] bf16 ----------
__global__ __launch_bounds__(256) void wtrans(const float* __restrict__ W,
                                              u16* __restrict__ WT, int K, int N) {
  __shared__ float t[32][33];
  int n0 = blockIdx.x * 32, k0 = blockIdx.y * 32;
  int tx = threadIdx.x, ty = threadIdx.y;
#pragma unroll
  for (int r = 0; r < 4; r++)
    t[ty + r * 8][tx] = W[(long)(k0 + ty + r * 8) * N + n0 + tx];
  __syncthreads();
#pragma unroll
  for (int r = 0; r < 4; r++)
    WT[(long)(n0 + ty + r * 8) * K + k0 + tx] = f2bf(t[tx][ty + r * 8]);
}

// ---------- V transpose: [b, n, head_off + h*64 + d] -> [bh][d][n] ----------
__global__ __launch_bounds__(256) void vtrans(const u16* __restrict__ src,
                                              u16* __restrict__ dst,
                                              int rows, int rstride, int head_off, int H) {
  __shared__ u16 t[64][65];
  int bh = blockIdx.y;
  int b = bh / H, h = bh % H;
  long n0 = (long)blockIdx.x * 64;
  const u16* s = src + (long)b * rows * rstride + head_off + h * 64;
  int q = threadIdx.x >> 6, ln = threadIdx.x & 63;
#pragma unroll
  for (int r = 0; r < 16; r++) {
    int nl = q * 16 + r;
    t[nl][ln] = s[(n0 + nl) * (long)rstride + ln];
  }
  __syncthreads();
  u16* d = dst + (long)bh * 64 * rows;
#pragma unroll
  for (int r = 0; r < 16; r++) {
    int dd = q * 16 + r;
    d[(long)dd * rows + n0 + ln] = t[ln][dd];
  }
}

// ---------- gemm4: merged phase + pipelined counted-lgkm gates ----------
// BM=256, BK=64 (2 K-halves), 8 waves (WM x WN), wave tile (BM/WM) x (BN/WN).
// One phase per K-half: { asm ds_read bf[NR] then af[MR] (order-pinned);
//   stage 1 half (A+B, LH=2+BLB gload_lds); setprio(1);
//   for mm: lgkmcnt(MR-1-mm)+sched_barrier -> NR MFMA  (drain hides under MFMA);
//   setprio(0); counted vmcnt; s_barrier }.
// vmcnt ledger: steady 2*LH, tail LH then 0. Buffer overwrite always separated
// from last reader by the phase-end barrier (audited half-by-half).
template <int BN, int WM, int GELU>
__global__ __launch_bounds__(512, 1) void gemm4(const u16* __restrict__ A,
                                                const u16* __restrict__ BT,
                                                const float* __restrict__ bias,
                                                float* __restrict__ outF,
                                                u16* __restrict__ outB,
                                                int M, int N, int K) {
  constexpr int BM = 256;
  constexpr int WN = 8 / WM;
  constexpr int MR = BM / (16 * WM);
  constexpr int NR = BN / (16 * WN);
  constexpr int BLB = BN / 128;   // B gload_lds per thread per half
  constexpr int LH = 2 + BLB;     // loads per half (A + B)
  __shared__ __align__(16) u16 Al[2][2][BM * 32];
  __shared__ __align__(16) u16 Bl[2][2][BN * 32];
  const int tid = threadIdx.x;
  const int w = tid >> 6, l = tid & 63;
  const int wr = w / WN, wc = w % WN;
  const int lr = l & 15, lg = l >> 4;

  // XCD mapping: each XCD owns nx/8 contiguous bx (A slabs), streams by
  const int nx = M >> 8;
  const int gpx = nx >> 3;
  const int hgt = blockIdx.x;
  const int xcd = hgt & 7, j = hgt >> 3;
  const int bx = xcd * gpx + (j % gpx);
  const int by = j / gpx;
  const long m0 = (long)bx * BM, n0 = (long)by * BN;

  const int nt = K >> 6;

  // stage source bases (inverse-swizzled global, linear LDS dest)
  const u16* baseA[2];
#pragma unroll
  for (int rr = 0; rr < 2; rr++) {
    int e = rr * 512 + tid, row = e >> 2;
    int kk = ((e & 3) - (row >> 1)) & 3;
    baseA[rr] = A + (m0 + row) * (long)K + kk * 8;
  }
  const u16* baseB[BLB];
#pragma unroll
  for (int rr = 0; rr < BLB; rr++) {
    int e = rr * 512 + tid, row = e >> 2;
    int kk = ((e & 3) - (row >> 1)) & 3;
    baseB[rr] = BT + (n0 + row) * (long)K + kk * 8;
  }

  auto stage = [&](int buf, int kh, int t) {
    if (t < nt) {
#pragma unroll
      for (int rr = 0; rr < 2; rr++)
        gload_lds16(baseA[rr] + (long)t * 64 + kh * 32, &Al[buf][kh][(rr * 512 + tid) * 8]);
#pragma unroll
      for (int rr = 0; rr < BLB; rr++)
        gload_lds16(baseB[rr] + (long)t * 64 + kh * 32, &Bl[buf][kh][(rr * 512 + tid) * 8]);
    }
  };

  f32x4 acc[MR][NR];
#pragma unroll
  for (int i = 0; i < MR; i++)
#pragma unroll
    for (int nn = 0; nn < NR; nn++) acc[i][nn] = (f32x4){0.f, 0.f, 0.f, 0.f};

  // prologue: 3 halves in flight
  stage(0, 0, 0); stage(0, 1, 0); stage(1, 0, 1);
  wait_vm<2 * LH>();
  SBAR(); __builtin_amdgcn_s_barrier(); SBAR();

  for (int t = 0; t < nt; ++t) {
    const int bt = t & 1, nb = bt ^ 1;
#pragma unroll
    for (int kh = 0; kh < 2; kh++) {
      const u16* Ah = &Al[bt][kh][0];
      const u16* Bh = &Bl[bt][kh][0];
      short8 bf[NR], af[MR];
      // order-pinned reads: bf first, af ascending (counted gates rely on this)
#pragma unroll
      for (int nn = 0; nn < NR; nn++) {
        int row = wc * (BN / WN) + nn * 16 + lr;
        bf[nn] = ds_read128(lds_off(&Bh[row * 32 + (((lg + (row >> 1)) & 3) << 3)]));
      }
#pragma unroll
      for (int mm = 0; mm < MR; mm++) {
        int row = wr * (BM / WM) + mm * 16 + lr;
        af[mm] = ds_read128(lds_off(&Ah[row * 32 + (((lg + (row >> 1)) & 3) << 3)]));
      }
      if (kh == 0) stage(nb, 1, t + 1); else stage(bt, 0, t + 2);
      __builtin_amdgcn_s_setprio(1);
#pragma unroll
      for (int mm = 0; mm < MR; mm++) {
        lgkm_gate(MR - 1 - mm);
        SBAR();
#pragma unroll
        for (int nn = 0; nn < NR; nn++)
          acc[mm][nn] = __builtin_amdgcn_mfma_f32_16x16x32_bf16(af[mm], bf[nn], acc[mm][nn], 0, 0, 0);
      }
      __builtin_amdgcn_s_setprio(0);
      // counted vmcnt for the NEXT phase's half
      if (kh == 0) {
        if (t == nt - 1) wait_vm<0>(); else wait_vm<2 * LH>();
      } else {
        if (t + 2 < nt) wait_vm<2 * LH>();
        else if (t + 1 < nt) wait_vm<LH>();
      }
      SBAR(); __builtin_amdgcn_s_barrier(); SBAR();
    }
  }

  // epilogue: nn innermost so adjacent 32B col-segments merge into 64B writes
  float bv[NR];
#pragma unroll
  for (int nn = 0; nn < NR; nn++)
    bv[nn] = bias ? bias[n0 + wc * (BN / WN) + nn * 16 + lr] : 0.f;
#pragma unroll
  for (int mm = 0; mm < MR; mm++) {
#pragma unroll
    for (int i = 0; i < 4; i++) {
      const long row = m0 + wr * (BM / WM) + mm * 16 + lg * 4 + i;
#pragma unroll
      for (int nn = 0; nn < NR; nn++) {
        const long col = n0 + wc * (BN / WN) + nn * 16 + lr;
        float v = acc[mm][nn][i] + bv[nn];
        if (GELU) v = 0.5f * v * (1.f + erff(v * 0.70710678118654752f));
        if (outF) outF[row * N + col] = v;
        if (outB) outB[row * N + col] = f2bf(v);
      }
    }
  }
}

// ---------- flash attention v3: 4-wave blocks, LDS-shared K/V, double-buffered ----------
template <bool CAUSAL>
__global__ __launch_bounds__(256, 4) void attn3(const u16* __restrict__ qb, long q_bstride, int q_rstride,
                                                const u16* __restrict__ kbp, long k_bstride, int k_rstride,
                                                const u16* __restrict__ vt,
                                                u16* __restrict__ yb, long y_bstride, int y_rstride,
                                                int Nk, int H) {
  __shared__ __align__(16) u16 Kl[2][2048];
  __shared__ __align__(16) u16 Vl[2][2048];
  const int tid = threadIdx.x;
  const int w = tid >> 6, l = tid & 63;
  const int qi = l & 31, hi = l >> 5;

  const int nwg = gridDim.x;
  const int chunk = nwg >> 3;
  const int nb = (blockIdx.x & 7) * chunk + (blockIdx.x >> 3);
  const int bh = nb >> 3;
  const int bx6 = nb & 7;
  const int bx = (bx6 & 1) ? (7 - (bx6 >> 1)) : (bx6 >> 1);
  const int b = bh / H, h = bh % H;
  const int qr0 = bx * 128 + w * 32;
  const u16* qp = qb + (long)b * q_bstride + h * 64;
  const u16* kp = kbp + (long)b * k_bstride + h * 64;
  const u16* vp = vt + (long)bh * 64 * Nk;
  const float CL = 0.125f * 1.44269504088896340736f;

  const u16* qrow = qp + (long)(qr0 + qi) * q_rstride + hi * 8;
  short8 qf0 = *(const short8*)(qrow);
  short8 qf1 = *(const short8*)(qrow + 16);
  short8 qf2 = *(const short8*)(qrow + 32);
  short8 qf3 = *(const short8*)(qrow + 48);

  f32x16 ot0, ot1;
#pragma unroll
  for (int i = 0; i < 16; i++) { ot0[i] = 0.f; ot1[i] = 0.f; }
  float m_run = -INFINITY, l_run = 0.f;

  const int krow_ = tid >> 3, kcb_ = (tid & 7) ^ (krow_ & 7);
  const int vrow_ = tid >> 2, vcb_ = (tid & 3) ^ (vrow_ & 3);
  const u16* kg = kp + (long)krow_ * k_rstride + kcb_ * 8;
  const u16* vg = vp + (long)vrow_ * Nk + vcb_ * 8;

  const int ntiles = CAUSAL ? (bx * 4 + 4) : (Nk >> 5);
  const int mytile = bx * 4 + w;

  gload_lds16(kg, &Kl[0][tid * 8]);
  gload_lds16(vg, &Vl[0][tid * 8]);
  __syncthreads();

  for (int t = 0; t < ntiles; ++t) {
    const int cur = t & 1;
    if (t + 1 < ntiles) {
      gload_lds16(kg + (t + 1) * 32 * (long)k_rstride, &Kl[cur ^ 1][tid * 8]);
      gload_lds16(vg + (t + 1) * 32, &Vl[cur ^ 1][tid * 8]);
    }
    if (!CAUSAL || t <= mytile) {
      const int kb0 = t * 32;
      const bool dmask = CAUSAL && (t == mytile);
      short8 kf[4];
#pragma unroll
      for (int ks = 0; ks < 4; ks++)
        kf[ks] = *(const short8*)&Kl[cur][(qi << 6) + (((2 * ks + hi) ^ (qi & 7)) << 3)];
      f32x16 sc;
#pragma unroll
      for (int i = 0; i < 16; i++) sc[i] = 0.f;
      sc = __builtin_amdgcn_mfma_f32_32x32x16_bf16(kf[0], qf0, sc, 0, 0, 0);
      sc = __builtin_amdgcn_mfma_f32_32x32x16_bf16(kf[1], qf1, sc, 0, 0, 0);
      sc = __builtin_amdgcn_mfma_f32_32x32x16_bf16(kf[2], qf2, sc, 0, 0, 0);
      sc = __builtin_amdgcn_mfma_f32_32x32x16_bf16(kf[3], qf3, sc, 0, 0, 0);
      if (dmask) {
#pragma unroll
        for (int r = 0; r < 16; r++) {
          int key = kb0 + (r & 3) + 8 * (r >> 2) + 4 * hi;
          if (key > qr0 + qi) sc[r] = -INFINITY;
        }
      }
      float mx = sc[0];
#pragma unroll
      for (int r = 1; r < 16; r++) mx = fmaxf(mx, sc[r]);
      { float a = mx, bb2 = mx; plswapf(a, bb2); mx = fmaxf(a, bb2); }
      float mnew = fmaxf(m_run, mx);
      float alpha = exp2f((m_run - mnew) * CL);
      m_run = mnew;
      float p[16];
      float ssum = 0.f;
#pragma unroll
      for (int r = 0; r < 16; r++) { p[r] = exp2f((sc[r] - mnew) * CL); ssum += p[r]; }
      { float a = ssum, bb2 = ssum; plswapf(a, bb2); ssum = a + bb2; }
      l_run = l_run * alpha + ssum;
#pragma unroll
      for (int i = 0; i < 16; i++) { ot0[i] *= alpha; ot1[i] *= alpha; }
      u32 w0 = cvtpk_bf16(p[0], p[1]);
      u32 w1 = cvtpk_bf16(p[2], p[3]);
      u32 w2 = cvtpk_bf16(p[4], p[5]);
      u32 w3 = cvtpk_bf16(p[6], p[7]);
      plswap32(w0, w2);
      plswap32(w1, w3);
      u32 w4 = cvtpk_bf16(p[8], p[9]);
      u32 w5 = cvtpk_bf16(p[10], p[11]);
      u32 w6 = cvtpk_bf16(p[12], p[13]);
      u32 w7 = cvtpk_bf16(p[14], p[15]);
      plswap32(w4, w6);
      plswap32(w5, w7);
      union { u32 u[4]; short8 s; } ua0, ua1;
      ua0.u[0] = w0; ua0.u[1] = w1; ua0.u[2] = w2; ua0.u[3] = w3;
      ua1.u[0] = w4; ua1.u[1] = w5; ua1.u[2] = w6; ua1.u[3] = w7;
      short8 va00 = *(const short8*)&Vl[cur][(qi << 5) + (((hi) ^ (qi & 3)) << 3)];
      short8 va01 = *(const short8*)&Vl[cur][(qi << 5) + (((2 + hi) ^ (qi & 3)) << 3)];
      short8 va10 = *(const short8*)&Vl[cur][((qi + 32) << 5) + (((hi) ^ (qi & 3)) << 3)];
      short8 va11 = *(const short8*)&Vl[cur][((qi + 32) << 5) + (((2 + hi) ^ (qi & 3)) << 3)];
      ot0 = __builtin_amdgcn_mfma_f32_32x32x16_bf16(va00, ua0.s, ot0, 0, 0, 0);
      ot0 = __builtin_amdgcn_mfma_f32_32x32x16_bf16(va01, ua1.s, ot0, 0, 0, 0);
      ot1 = __builtin_amdgcn_mfma_f32_32x32x16_bf16(va10, ua0.s, ot1, 0, 0, 0);
      ot1 = __builtin_amdgcn_mfma_f32_32x32x16_bf16(va11, ua1.s, ot1, 0, 0, 0);
    }
    __syncthreads();
  }

  float inv = 1.f / l_run;
  u16* yp = yb + (long)b * y_bstride + h * 64 + (long)(qr0 + qi) * y_rstride;
#pragma unroll
  for (int g = 0; g < 4; g++) {
    uint2 s0;
    s0.x = cvtpk_bf16(ot0[4 * g + 0] * inv, ot0[4 * g + 1] * inv);
    s0.y = cvtpk_bf16(ot0[4 * g + 2] * inv, ot0[4 * g + 3] * inv);
    *(uint2*)(yp + 8 * g + 4 * hi) = s0;
    uint2 s1;
    s1.x = cvtpk_bf16(ot1[4 * g + 0] * inv, ot1[4 * g + 1] * inv);
    s1.y = cvtpk_bf16(ot1[4 * g + 2] * inv, ot1[4 * g + 3] * inv);
    *(uint2*)(yp + 32 + 8 * g + 4 * hi) = s1;
  }
}

// ---------- layernorm (optionally + residual), f32 in, f32+bf16 out ----------
__global__ __launch_bounds__(256) void ln_k(const float* x, const float* res,
                                            const float* g, const float* bb,
                                            float* outF, u16* outB, int C) {
  __shared__ float red[8];
  long row = blockIdx.x;
  const float* xp = x + row * C;
  int i0 = threadIdx.x * 4;
  float4 v = *(const float4*)(xp + i0);
  if (res) {
    float4 r = *(const float4*)(res + row * C + i0);
    v.x += r.x; v.y += r.y; v.z += r.z; v.w += r.w;
  }
  float s = v.x + v.y + v.z + v.w;
  float sq = v.x * v.x + v.y * v.y + v.z * v.z + v.w * v.w;
#pragma unroll
  for (int off = 1; off < 64; off <<= 1) {
    s += __shfl_xor(s, off, 64);
    sq += __shfl_xor(sq, off, 64);
  }
  int w = threadIdx.x >> 6, l = threadIdx.x & 63;
  if (l == 0) { red[w] = s; red[4 + w] = sq; }
  __syncthreads();
  s = red[0] + red[1] + red[2] + red[3];
  sq = red[4] + red[5] + red[6] + red[7];
  float mean = s * (1.f / 1024.f);
  float var = sq * (1.f / 1024.f) - mean * mean;
  float rstd = rsqrtf(var + 1e-5f);
  float4 gv = *(const float4*)(g + i0);
  float4 bv = *(const float4*)(bb + i0);
  float o0 = (v.x - mean) * rstd * gv.x + bv.x;
  float o1 = (v.y - mean) * rstd * gv.y + bv.y;
  float o2 = (v.z - mean) * rstd * gv.z + bv.z;
  float o3 = (v.w - mean) * rstd * gv.w + bv.w;
  if (outF) {
    float4 ov; ov.x = o0; ov.y = o1; ov.z = o2; ov.w = o3;
    *(float4*)(outF + row * C + i0) = ov;
  }
  if (outB) {
    unsigned long long p = (unsigned long long)f2bf(o0) |
                           ((unsigned long long)f2bf(o1) << 16) |
                           ((unsigned long long)f2bf(o2) << 32) |
                           ((unsigned long long)f2bf(o3) << 48);
    *(unsigned long long*)(outB + row * C + i0) = p;
  }
}

// ---------- launcher ----------
extern "C" void kernel_launch(void* const* d_in, const int* in_sizes, int n_in,
                              void* d_out, int out_size, void* d_ws, size_t ws_size,
                              hipStream_t stream) {
  const int B = 8, N = 1024, T = 512, C = 1024, H = 16;
  const float* prev = (const float*)d_in[0];
  const float* enc = (const float*)d_in[1];
  const float* sa_w = (const float*)d_in[2];
  const float* sa_b = (const float*)d_in[3];
  const float* sa_pw = (const float*)d_in[4];
  const float* sa_pb = (const float*)d_in[5];
  const float* caq_w = (const float*)d_in[6];
  const float* caq_b = (const float*)d_in[7];
  const float* cakv_w = (const float*)d_in[8];
  const float* cakv_b = (const float*)d_in[9];
  const float* ca_pw = (const float*)d_in[10];
  const float* ca_pb = (const float*)d_in[11];
  const float* fc_w = (const float*)d_in[12];
  const float* fc_b = (const float*)d_in[13];
  const float* proj_w = (const float*)d_in[14];
  const float* proj_b = (const float*)d_in[15];
  const float* ln1_g = (const float*)d_in[16];
  const float* ln1_b = (const float*)d_in[17];
  const float* ln2_g = (const float*)d_in[18];
  const float* ln2_b = (const float*)d_in[19];
  const float* ln3_g = (const float*)d_in[20];
  const float* ln3_b = (const float*)d_in[21];

  char* ws = (char*)d_ws;
  u16* wT_sa   = (u16*)(ws + 0);               // [3072,1024]
  u16* wT_sapw = (u16*)(ws + 6291456);         // [1024,1024]
  u16* wT_caq  = (u16*)(ws + 8388608);         // [1024,1024]
  u16* wT_cakv = (u16*)(ws + 10485760);        // [2048,1024]
  u16* wT_capw = (u16*)(ws + 14680064);        // [1024,1024]
  u16* wT_fc   = (u16*)(ws + 16777216);        // [4096,1024]
  u16* wT_proj = (u16*)(ws + 25165824);        // [1024,4096]
  u16* abf   = (u16*)(ws + 33554432);
  u16* encbf = (u16*)(ws + 50331648);
  u16* qkv   = (u16*)(ws + 58720256);
  u16* vt1   = (u16*)(ws + 109051904);
  u16* ybf   = (u16*)(ws + 125829120);
  float* pf32 = (float*)(ws + 142606336);
  float* x1f  = (float*)(ws + 176160768);
  u16* x1bf  = (u16*)(ws + 209715200);
  u16* kvbf  = (u16*)(ws + 226492416);
  u16* y2bf  = abf;
  u16* vt2   = encbf;
  u16* q2bf  = ybf;
  u16* hbf   = qkv;

  cvt_f32_bf16<<<8192, 256, 0, stream>>>(prev, abf, (long)B * N * C);
  cvt_f32_bf16<<<4096, 256, 0, stream>>>(enc, encbf, (long)B * T * C);
  wtrans<<<dim3(96, 32), dim3(32, 8), 0, stream>>>(sa_w, wT_sa, 1024, 3072);
  wtrans<<<dim3(32, 32), dim3(32, 8), 0, stream>>>(sa_pw, wT_sapw, 1024, 1024);
  wtrans<<<dim3(32, 32), dim3(32, 8), 0, stream>>>(caq_w, wT_caq, 1024, 1024);
  wtrans<<<dim3(64, 32), dim3(32, 8), 0, stream>>>(cakv_w, wT_cakv, 1024, 2048);
  wtrans<<<dim3(32, 32), dim3(32, 8), 0, stream>>>(ca_pw, wT_capw, 1024, 1024);
  wtrans<<<dim3(128, 32), dim3(32, 8), 0, stream>>>(fc_w, wT_fc, 1024, 4096);
  wtrans<<<dim3(32, 128), dim3(32, 8), 0, stream>>>(proj_w, wT_proj, 4096, 1024);
  // qkv: M=8192 N=3072 K=1024
  gemm4<128, 4, 0><<<768, 512, 0, stream>>>(abf, wT_sa, sa_b, nullptr, qkv, 8192, 3072, 1024);
  vtrans<<<dim3(16, 128), 256, 0, stream>>>(qkv, vt1, 1024, 3 * C, 2 * C, H);
  attn3<true><<<dim3(1024), 256, 0, stream>>>(qkv, (long)N * 3 * C, 3 * C,
                                              qkv + C, (long)N * 3 * C, 3 * C,
                                              vt1, ybf, (long)N * C, C, N, H);
  gemm4<128, 4, 0><<<256, 512, 0, stream>>>(ybf, wT_sapw, sa_pb, pf32, nullptr, 8192, 1024, 1024);
  ln_k<<<8192, 256, 0, stream>>>(pf32, nullptr, ln1_g, ln1_b, x1f, x1bf, C);
  gemm4<128, 4, 0><<<256, 512, 0, stream>>>(x1bf, wT_caq, caq_b, nullptr, q2bf, 8192, 1024, 1024);
  gemm4<128, 4, 0><<<256, 512, 0, stream>>>(encbf, wT_cakv, cakv_b, nullptr, kvbf, 4096, 2048, 1024);
  vtrans<<<dim3(8, 128), 256, 0, stream>>>(kvbf, vt2, 512, 2 * C, C, H);
  attn3<false><<<dim3(1024), 256, 0, stream>>>(q2bf, (long)N * C, C,
                                               kvbf, (long)T * 2 * C, 2 * C,
                                               vt2, y2bf, (long)N * C, C, T, H);
  gemm4<128, 4, 0><<<256, 512, 0, stream>>>(y2bf, wT_capw, ca_pb, pf32, nullptr, 8192, 1024, 1024);
  ln_k<<<8192, 256, 0, stream>>>(pf32, x1f, ln2_g, ln2_b, x1f, x1bf, C);
  // fc: M=8192 N=4096 K=1024, GELU
  gemm4<256, 2, 1><<<512, 512, 0, stream>>>(x1bf, wT_fc, fc_b, nullptr, hbf, 8192, 4096, 1024);
  // proj: M=8192 N=1024 K=4096
  gemm4<128, 4, 0><<<256, 512, 0, stream>>>(hbf, wT_proj, proj_b, pf32, nullptr, 8192, 1024, 4096);
  ln_k<<<8192, 256, 0, stream>>>(pf32, x1f, ln3_g, ln3_b, (float*)d_out, nullptr, C);
}